// Round 2
// baseline (1175.475 us; speedup 1.0000x reference)
//
#include <hip/hip_runtime.h>
#include <hip/hip_bf16.h>
#include <math.h>

// Problem constants
#define NSQ   12      // b*F sequences
#define LQ    2048    // per-sequence length
#define DIMQ  384
#define DIQ   192     // d_in
#define RKQ   24      // dt rank
#define GROWS (NSQ*LQ) // 24576

__device__ __forceinline__ float siluf(float x) {
  return x / (1.0f + __expf(-x));
}
__device__ __forceinline__ float softplusf(float x) {
  return (x > 20.0f) ? x : log1pf(expf(x));
}

// ---------------------------------------------------------------------------
// K0: transpose small weight matrices for coalesced access later.
// xpw (56,192) -> xpw_t (192,56);  dtw (192,24) -> dtw_t (24,192)
__global__ void k_prep(const float* __restrict__ xpw, const float* __restrict__ dtw,
                       float* __restrict__ xpw_t, float* __restrict__ dtw_t) {
  int t = threadIdx.x + blockIdx.x * blockDim.x;
  int stride = blockDim.x * gridDim.x;
  for (int i = t; i < DIQ * 56; i += stride) {
    int d = i / 56, r = i % 56;
    xpw_t[i] = xpw[r * DIQ + d];
  }
  for (int i = t; i < RKQ * DIQ; i += stride) {
    int r = i / DIQ, d = i % DIQ;
    dtw_t[i] = dtw[d * RKQ + r];
  }
}

// ---------------------------------------------------------------------------
// K1: in_proj GEMM. C[m][c] = sum_k x[m][k]*W[c][k] + b[c], stored channel-major
// xp_t[(s*384+c)*2048 + p] with m = s*2048+p.  Tile M=128, N=64, K-step 16.
__launch_bounds__(256)
__global__ void k_inproj(const float* __restrict__ x, const float* __restrict__ w,
                         const float* __restrict__ bias, float* __restrict__ xp_t) {
  __shared__ float As[16][132];
  __shared__ float Bs[16][68];
  const int t = threadIdx.x;
  const int m0 = blockIdx.x * 128;
  const int n0 = blockIdx.y * 64;
  const int tx = t & 31, ty = t >> 5;     // micro-tile: m = tx*4+i, n = ty*8+j
  const int ml = t >> 2, kq = t & 3;      // staging indices
  float acc[4][8];
#pragma unroll
  for (int i = 0; i < 4; ++i)
#pragma unroll
    for (int j = 0; j < 8; ++j) acc[i][j] = 0.0f;

  for (int k0 = 0; k0 < 384; k0 += 16) {
    const float4 a0 = *(const float4*)&x[(size_t)(m0 + ml) * 384 + k0 + kq * 4];
    const float4 a1 = *(const float4*)&x[(size_t)(m0 + ml + 64) * 384 + k0 + kq * 4];
    const float4 b0 = *(const float4*)&w[(size_t)(n0 + ml) * 384 + k0 + kq * 4];
    __syncthreads();
    As[kq * 4 + 0][ml] = a0.x; As[kq * 4 + 1][ml] = a0.y;
    As[kq * 4 + 2][ml] = a0.z; As[kq * 4 + 3][ml] = a0.w;
    As[kq * 4 + 0][ml + 64] = a1.x; As[kq * 4 + 1][ml + 64] = a1.y;
    As[kq * 4 + 2][ml + 64] = a1.z; As[kq * 4 + 3][ml + 64] = a1.w;
    Bs[kq * 4 + 0][ml] = b0.x; Bs[kq * 4 + 1][ml] = b0.y;
    Bs[kq * 4 + 2][ml] = b0.z; Bs[kq * 4 + 3][ml] = b0.w;
    __syncthreads();
#pragma unroll
    for (int k = 0; k < 16; ++k) {
      const float4 av  = *(const float4*)&As[k][tx * 4];
      const float4 bv0 = *(const float4*)&Bs[k][ty * 8];
      const float4 bv1 = *(const float4*)&Bs[k][ty * 8 + 4];
      const float a4[4] = {av.x, av.y, av.z, av.w};
      const float b8[8] = {bv0.x, bv0.y, bv0.z, bv0.w, bv1.x, bv1.y, bv1.z, bv1.w};
#pragma unroll
      for (int i = 0; i < 4; ++i)
#pragma unroll
        for (int j = 0; j < 8; ++j) acc[i][j] = fmaf(a4[i], b8[j], acc[i][j]);
    }
  }
  const int s = m0 >> 11;
  const int p0 = m0 & 2047;
#pragma unroll
  for (int j = 0; j < 8; ++j) {
    const int c = n0 + ty * 8 + j;
    const float bv = bias[c];
    float4 v;
    v.x = acc[0][j] + bv; v.y = acc[1][j] + bv;
    v.z = acc[2][j] + bv; v.w = acc[3][j] + bv;
    *(float4*)&xp_t[((size_t)s * 384 + c) * 2048 + p0 + tx * 4] = v;
  }
}

// ---------------------------------------------------------------------------
// K2: grouped conv (k=3, SAME) + SiLU.  out ch d uses input ch 2d, 2d+1.
__global__ void k_conv(const float* __restrict__ xp_t, const float* __restrict__ cw,
                       const float* __restrict__ cb, float* __restrict__ xc) {
  const int idx = blockIdx.x * 256 + threadIdx.x;      // (s*192+d)*2048 + p
  const int p = idx & 2047;
  const int sd = idx >> 11;
  const int d = sd % DIQ, s = sd / DIQ;
  const float* r0 = &xp_t[((size_t)s * 384 + 2 * d) * 2048];
  const float* r1 = r0 + 2048;
  const float w00 = cw[d * 6 + 0], w01 = cw[d * 6 + 1], w02 = cw[d * 6 + 2];
  const float w10 = cw[d * 6 + 3], w11 = cw[d * 6 + 4], w12 = cw[d * 6 + 5];
  float acc = cb[d];
  if (p > 0)    acc += w00 * r0[p - 1] + w10 * r1[p - 1];
  acc += w01 * r0[p] + w11 * r1[p];
  if (p < 2047) acc += w02 * r0[p + 1] + w12 * r1[p + 1];
  xc[idx] = siluf(acc);
}

// ---------------------------------------------------------------------------
// K3: fused x_proj (K=192 -> 56 rows) + dt_proj (K=24 -> 192) + softplus.
// Block: 64 l-positions of one s. Outputs: delta (s,d,l), bc[g][0:16]=B, [16:32]=C.
__launch_bounds__(256)
__global__ void k_xproj(const float* __restrict__ xc, const float* __restrict__ xpw_t,
                        const float* __restrict__ dtw_t, const float* __restrict__ dtb,
                        float* __restrict__ delta, float* __restrict__ bc) {
  __shared__ float As[16][68];     // [k=d][m=l] tile of u
  __shared__ float Bs[16][64];     // [k=d][r] (r padded 56->64 with 0)
  __shared__ float xd[24][68];     // dt rows of x_dbl
  __shared__ float Dtw[24][192];   // dt_proj_w transposed
  const int t = threadIdx.x;
  const int m0 = blockIdx.x * 64;
  const int s = m0 >> 11, l0 = m0 & 2047;
  for (int i = t; i < 24 * 192; i += 256) Dtw[i / 192][i % 192] = dtw_t[i];
  const int tx = t & 15, ty = t >> 4;   // micro: m=tx*4+i, n=ty*4+j
  const int lk = t >> 4, mq = t & 15;
  float acc[4][4];
#pragma unroll
  for (int i = 0; i < 4; ++i)
#pragma unroll
    for (int j = 0; j < 4; ++j) acc[i][j] = 0.0f;

  for (int k0 = 0; k0 < 192; k0 += 16) {
    const float4 a = *(const float4*)&xc[((size_t)s * 192 + k0 + lk) * 2048 + l0 + mq * 4];
    float4 b;
    if (mq < 14) b = *(const float4*)&xpw_t[(size_t)(k0 + lk) * 56 + mq * 4];
    else         b = make_float4(0.f, 0.f, 0.f, 0.f);
    __syncthreads();
    *(float4*)&As[lk][mq * 4] = a;
    *(float4*)&Bs[lk][mq * 4] = b;
    __syncthreads();
#pragma unroll
    for (int k = 0; k < 16; ++k) {
      const float4 av = *(const float4*)&As[k][tx * 4];
      const float4 bv = *(const float4*)&Bs[k][ty * 4];
      const float a4[4] = {av.x, av.y, av.z, av.w};
      const float b4[4] = {bv.x, bv.y, bv.z, bv.w};
#pragma unroll
      for (int i = 0; i < 4; ++i)
#pragma unroll
        for (int j = 0; j < 4; ++j) acc[i][j] = fmaf(a4[i], b4[j], acc[i][j]);
    }
  }
  // scatter: rows 0..23 -> xd (LDS), rows 24..55 -> B/C global, rows 56..63 dropped
  const int nbase = ty * 4;
  if (nbase < 24) {
#pragma unroll
    for (int j = 0; j < 4; ++j)
#pragma unroll
      for (int i = 0; i < 4; ++i) xd[nbase + j][tx * 4 + i] = acc[i][j];
  } else if (nbase < 56) {
#pragma unroll
    for (int i = 0; i < 4; ++i) {
      float4 v; v.x = acc[i][0]; v.y = acc[i][1]; v.z = acc[i][2]; v.w = acc[i][3];
      *(float4*)&bc[(size_t)(m0 + tx * 4 + i) * 32 + (nbase - 24)] = v;
    }
  }
  __syncthreads();
  // stage 2: delta[d][l] = softplus(sum_r dtw[d][r]*xd[r][l] + dtb[d])
#pragma unroll
  for (int dc = 0; dc < 3; ++dc) {
    float a2[4][4];
#pragma unroll
    for (int i = 0; i < 4; ++i)
#pragma unroll
      for (int j = 0; j < 4; ++j) a2[i][j] = 0.0f;
    const int d0 = dc * 64 + ty * 4;
#pragma unroll
    for (int r = 0; r < 24; ++r) {
      const float4 av = *(const float4*)&xd[r][tx * 4];
      const float4 bv = *(const float4*)&Dtw[r][d0];
      const float a4[4] = {av.x, av.y, av.z, av.w};
      const float b4[4] = {bv.x, bv.y, bv.z, bv.w};
#pragma unroll
      for (int i = 0; i < 4; ++i)
#pragma unroll
        for (int j = 0; j < 4; ++j) a2[i][j] = fmaf(a4[i], b4[j], a2[i][j]);
    }
#pragma unroll
    for (int j = 0; j < 4; ++j) {
      const int d = d0 + j;
      const float bb = dtb[d];
      float4 v;
      v.x = softplusf(a2[0][j] + bb);
      v.y = softplusf(a2[1][j] + bb);
      v.z = softplusf(a2[2][j] + bb);
      v.w = softplusf(a2[3][j] + bb);
      *(float4*)&delta[((size_t)s * 192 + d) * 2048 + l0 + tx * 4] = v;
    }
  }
}

// ---------------------------------------------------------------------------
// K4: bidirectional selective scan. Block = (16 channels x 16 states), one dir.
// h = exp(delta*a)*h + delta*u*B ; y = sum_n h*C_n (shfl reduce over 16 lanes).
__launch_bounds__(256)
__global__ void k_scan(const float* __restrict__ delta, const float* __restrict__ xc,
                       const float* __restrict__ bc, const float* __restrict__ A_log,
                       const float* __restrict__ Ab_log, float* __restrict__ yf,
                       float* __restrict__ yb) {
  __shared__ float ys[16][64];
  const int t = threadIdx.x;
  const int dl = t >> 4;           // local channel 0..15
  const int n = t & 15;            // state 0..15
  const int dg = blockIdx.x;       // channel group 0..11
  const int s = blockIdx.y;        // sequence 0..11
  const int dir = blockIdx.z;      // 0 fwd, 1 bwd
  const int d = dg * 16 + dl;
  const float a = -__expf((dir ? Ab_log : A_log)[d * 16 + n]);
  const float* dp = &delta[((size_t)s * 192 + d) * 2048];
  const float* up = &xc[((size_t)s * 192 + d) * 2048];
  const float* bp = &bc[(size_t)s * 2048 * 32];
  float* yrow = &(dir ? yb : yf)[((size_t)s * 192 + d) * 2048];
  float h = 0.0f;
  for (int blk = 0; blk < 32; ++blk) {
#pragma unroll 4
    for (int q = 0; q < 64; ++q) {
      const int l = blk * 64 + q;
      const int lf = dir ? (2047 - l) : l;
      const float dlt = dp[lf];
      const float u = up[lf];
      const float bn = bp[(size_t)lf * 32 + n];
      const float cn = bp[(size_t)lf * 32 + 16 + n];
      h = fmaf(__expf(dlt * a), h, dlt * u * bn);
      float yv = h * cn;
      yv += __shfl_xor(yv, 1);
      yv += __shfl_xor(yv, 2);
      yv += __shfl_xor(yv, 4);
      yv += __shfl_xor(yv, 8);
      if (n == 0) ys[dl][lf & 63] = yv;
    }
    __syncthreads();
    const int base = dir ? (2048 - (blk + 1) * 64) : blk * 64;
    const float4 v = *(const float4*)&ys[dl][n * 4];
    *(float4*)&yrow[base + n * 4] = v;
    __syncthreads();
  }
}

// ---------------------------------------------------------------------------
// K5: out_proj GEMM with fused concat: ch<192 -> yf+yb+2*D*u ; ch>=192 -> u (=z).
__launch_bounds__(256)
__global__ void k_outproj(const float* __restrict__ yf, const float* __restrict__ yb,
                          const float* __restrict__ xc, const float* __restrict__ Dvec,
                          const float* __restrict__ w, const float* __restrict__ bias,
                          float* __restrict__ out) {
  __shared__ float As[16][132];
  __shared__ float Bs[16][68];
  const int t = threadIdx.x;
  const int m0 = blockIdx.x * 128;
  const int n0 = blockIdx.y * 64;
  const int s = m0 >> 11, l0 = m0 & 2047;
  const int tx = t & 31, ty = t >> 5;
  const int ck = t >> 4, mq = t & 15;
  const int nl = t >> 2, kq = t & 3;
  float acc[4][8];
#pragma unroll
  for (int i = 0; i < 4; ++i)
#pragma unroll
    for (int j = 0; j < 8; ++j) acc[i][j] = 0.0f;

  for (int k0 = 0; k0 < 384; k0 += 16) {
    const int c = k0 + ck;
    float4 av0, av1;
    if (c < 192) {
      const size_t off = ((size_t)s * 192 + c) * 2048 + l0;
      const float dv2 = 2.0f * Dvec[c];
      const float4 f0 = *(const float4*)&yf[off + mq * 4];
      const float4 g0 = *(const float4*)&yb[off + mq * 4];
      const float4 u0 = *(const float4*)&xc[off + mq * 4];
      av0.x = f0.x + g0.x + dv2 * u0.x; av0.y = f0.y + g0.y + dv2 * u0.y;
      av0.z = f0.z + g0.z + dv2 * u0.z; av0.w = f0.w + g0.w + dv2 * u0.w;
      const float4 f1 = *(const float4*)&yf[off + (mq + 16) * 4];
      const float4 g1 = *(const float4*)&yb[off + (mq + 16) * 4];
      const float4 u1 = *(const float4*)&xc[off + (mq + 16) * 4];
      av1.x = f1.x + g1.x + dv2 * u1.x; av1.y = f1.y + g1.y + dv2 * u1.y;
      av1.z = f1.z + g1.z + dv2 * u1.z; av1.w = f1.w + g1.w + dv2 * u1.w;
    } else {
      const size_t off = ((size_t)s * 192 + (c - 192)) * 2048 + l0;
      av0 = *(const float4*)&xc[off + mq * 4];
      av1 = *(const float4*)&xc[off + (mq + 16) * 4];
    }
    const float4 b0 = *(const float4*)&w[(size_t)(n0 + nl) * 384 + k0 + kq * 4];
    __syncthreads();
    *(float4*)&As[ck][mq * 4] = av0;
    *(float4*)&As[ck][(mq + 16) * 4] = av1;
    Bs[kq * 4 + 0][nl] = b0.x; Bs[kq * 4 + 1][nl] = b0.y;
    Bs[kq * 4 + 2][nl] = b0.z; Bs[kq * 4 + 3][nl] = b0.w;
    __syncthreads();
#pragma unroll
    for (int k = 0; k < 16; ++k) {
      const float4 av  = *(const float4*)&As[k][tx * 4];
      const float4 bv0 = *(const float4*)&Bs[k][ty * 8];
      const float4 bv1 = *(const float4*)&Bs[k][ty * 8 + 4];
      const float a4[4] = {av.x, av.y, av.z, av.w};
      const float b8[8] = {bv0.x, bv0.y, bv0.z, bv0.w, bv1.x, bv1.y, bv1.z, bv1.w};
#pragma unroll
      for (int i = 0; i < 4; ++i)
#pragma unroll
        for (int j = 0; j < 8; ++j) acc[i][j] = fmaf(a4[i], b8[j], acc[i][j]);
    }
  }
  const float4 bb0 = *(const float4*)&bias[n0 + ty * 8];
  const float4 bb1 = *(const float4*)&bias[n0 + ty * 8 + 4];
#pragma unroll
  for (int i = 0; i < 4; ++i) {
    float4 v0, v1;
    v0.x = acc[i][0] + bb0.x; v0.y = acc[i][1] + bb0.y;
    v0.z = acc[i][2] + bb0.z; v0.w = acc[i][3] + bb0.w;
    v1.x = acc[i][4] + bb1.x; v1.y = acc[i][5] + bb1.y;
    v1.z = acc[i][6] + bb1.z; v1.w = acc[i][7] + bb1.w;
    const size_t ro = (size_t)(m0 + tx * 4 + i) * 384 + n0 + ty * 8;
    *(float4*)&out[ro] = v0;
    *(float4*)&out[ro + 4] = v1;
  }
}

// ---------------------------------------------------------------------------
extern "C" void kernel_launch(void* const* d_in, const int* in_sizes, int n_in,
                              void* d_out, int out_size, void* d_ws, size_t ws_size,
                              hipStream_t stream) {
  const float* x     = (const float*)d_in[0];
  const float* inw   = (const float*)d_in[1];
  const float* inb   = (const float*)d_in[2];
  const float* convw = (const float*)d_in[3];
  const float* convb = (const float*)d_in[4];
  const float* alog  = (const float*)d_in[5];
  const float* ablog = (const float*)d_in[6];
  const float* Dv    = (const float*)d_in[7];
  const float* xpw   = (const float*)d_in[8];
  const float* dtw   = (const float*)d_in[9];
  const float* dtb   = (const float*)d_in[10];
  const float* outw  = (const float*)d_in[11];
  const float* outb  = (const float*)d_in[12];
  float* out = (float*)d_out;

  float* ws = (float*)d_ws;
  float* xp_t  = ws;                       // 12*384*2048 = 9437184 floats
  float* xc    = xp_t + 9437184;           // 4718592
  float* delta = xc + 4718592;             // 4718592
  float* bc    = delta + 4718592;          // 24576*32 = 786432
  float* xpw_t = bc + 786432;              // 10752
  float* dtw_t = xpw_t + 10752;            // 4608
  // yf/yb alias xp_t: xp_t is dead after the conv kernel.
  float* yf = xp_t;
  float* yb = xp_t + 4718592;

  hipLaunchKernelGGL(k_prep,    dim3(8),        dim3(256), 0, stream, xpw, dtw, xpw_t, dtw_t);
  hipLaunchKernelGGL(k_inproj,  dim3(192, 6),   dim3(256), 0, stream, x, inw, inb, xp_t);
  hipLaunchKernelGGL(k_conv,    dim3(18432),    dim3(256), 0, stream, xp_t, convw, convb, xc);
  hipLaunchKernelGGL(k_xproj,   dim3(384),      dim3(256), 0, stream, xc, xpw_t, dtw_t, dtb, delta, bc);
  hipLaunchKernelGGL(k_scan,    dim3(12, 12, 2),dim3(256), 0, stream, delta, xc, bc, alog, ablog, yf, yb);
  hipLaunchKernelGGL(k_outproj, dim3(192, 6),   dim3(256), 0, stream, yf, yb, xc, Dv, outw, outb, out);
}

// Round 3
// 596.801 us; speedup vs baseline: 1.9696x; 1.9696x over previous
//
#include <hip/hip_runtime.h>
#include <hip/hip_bf16.h>
#include <math.h>

// Problem constants
#define NSQ   12      // b*F sequences
#define LQ    2048    // per-sequence length
#define DIMQ  384
#define DIQ   192     // d_in
#define RKQ   24      // dt rank
#define NCHK  16      // scan chunks
#define CLEN  128     // chunk length (LQ/NCHK)

__device__ __forceinline__ float siluf(float x) {
  return x / (1.0f + __expf(-x));
}
__device__ __forceinline__ float softplusf(float x) {
  return (x > 20.0f) ? x : log1pf(expf(x));
}

// ---------------------------------------------------------------------------
// K0: transpose small weight matrices for coalesced access later.
__global__ void k_prep(const float* __restrict__ xpw, const float* __restrict__ dtw,
                       float* __restrict__ xpw_t, float* __restrict__ dtw_t) {
  int t = threadIdx.x + blockIdx.x * blockDim.x;
  int stride = blockDim.x * gridDim.x;
  for (int i = t; i < DIQ * 56; i += stride) {
    int d = i / 56, r = i % 56;
    xpw_t[i] = xpw[r * DIQ + d];
  }
  for (int i = t; i < RKQ * DIQ; i += stride) {
    int r = i / DIQ, d = i % DIQ;
    dtw_t[i] = dtw[d * RKQ + r];
  }
}

// ---------------------------------------------------------------------------
// K1: in_proj GEMM, output channel-major xp_t[(s*384+c)*2048 + p].
__launch_bounds__(256)
__global__ void k_inproj(const float* __restrict__ x, const float* __restrict__ w,
                         const float* __restrict__ bias, float* __restrict__ xp_t) {
  __shared__ float As[16][132];
  __shared__ float Bs[16][68];
  const int t = threadIdx.x;
  const int m0 = blockIdx.x * 128;
  const int n0 = blockIdx.y * 64;
  const int tx = t & 31, ty = t >> 5;
  const int ml = t >> 2, kq = t & 3;
  float acc[4][8];
#pragma unroll
  for (int i = 0; i < 4; ++i)
#pragma unroll
    for (int j = 0; j < 8; ++j) acc[i][j] = 0.0f;

  for (int k0 = 0; k0 < 384; k0 += 16) {
    const float4 a0 = *(const float4*)&x[(size_t)(m0 + ml) * 384 + k0 + kq * 4];
    const float4 a1 = *(const float4*)&x[(size_t)(m0 + ml + 64) * 384 + k0 + kq * 4];
    const float4 b0 = *(const float4*)&w[(size_t)(n0 + ml) * 384 + k0 + kq * 4];
    __syncthreads();
    As[kq * 4 + 0][ml] = a0.x; As[kq * 4 + 1][ml] = a0.y;
    As[kq * 4 + 2][ml] = a0.z; As[kq * 4 + 3][ml] = a0.w;
    As[kq * 4 + 0][ml + 64] = a1.x; As[kq * 4 + 1][ml + 64] = a1.y;
    As[kq * 4 + 2][ml + 64] = a1.z; As[kq * 4 + 3][ml + 64] = a1.w;
    Bs[kq * 4 + 0][ml] = b0.x; Bs[kq * 4 + 1][ml] = b0.y;
    Bs[kq * 4 + 2][ml] = b0.z; Bs[kq * 4 + 3][ml] = b0.w;
    __syncthreads();
#pragma unroll
    for (int k = 0; k < 16; ++k) {
      const float4 av  = *(const float4*)&As[k][tx * 4];
      const float4 bv0 = *(const float4*)&Bs[k][ty * 8];
      const float4 bv1 = *(const float4*)&Bs[k][ty * 8 + 4];
      const float a4[4] = {av.x, av.y, av.z, av.w};
      const float b8[8] = {bv0.x, bv0.y, bv0.z, bv0.w, bv1.x, bv1.y, bv1.z, bv1.w};
#pragma unroll
      for (int i = 0; i < 4; ++i)
#pragma unroll
        for (int j = 0; j < 8; ++j) acc[i][j] = fmaf(a4[i], b8[j], acc[i][j]);
    }
  }
  const int s = m0 >> 11;
  const int p0 = m0 & 2047;
#pragma unroll
  for (int j = 0; j < 8; ++j) {
    const int c = n0 + ty * 8 + j;
    const float bv = bias[c];
    float4 v;
    v.x = acc[0][j] + bv; v.y = acc[1][j] + bv;
    v.z = acc[2][j] + bv; v.w = acc[3][j] + bv;
    *(float4*)&xp_t[((size_t)s * 384 + c) * 2048 + p0 + tx * 4] = v;
  }
}

// ---------------------------------------------------------------------------
// K2: grouped conv (k=3, SAME) + SiLU.
__global__ void k_conv(const float* __restrict__ xp_t, const float* __restrict__ cw,
                       const float* __restrict__ cb, float* __restrict__ xc) {
  const int idx = blockIdx.x * 256 + threadIdx.x;
  const int p = idx & 2047;
  const int sd = idx >> 11;
  const int d = sd % DIQ, s = sd / DIQ;
  const float* r0 = &xp_t[((size_t)s * 384 + 2 * d) * 2048];
  const float* r1 = r0 + 2048;
  const float w00 = cw[d * 6 + 0], w01 = cw[d * 6 + 1], w02 = cw[d * 6 + 2];
  const float w10 = cw[d * 6 + 3], w11 = cw[d * 6 + 4], w12 = cw[d * 6 + 5];
  float acc = cb[d];
  if (p > 0)    acc += w00 * r0[p - 1] + w10 * r1[p - 1];
  acc += w01 * r0[p] + w11 * r1[p];
  if (p < 2047) acc += w02 * r0[p + 1] + w12 * r1[p + 1];
  xc[idx] = siluf(acc);
}

// ---------------------------------------------------------------------------
// K3: fused x_proj + dt_proj + softplus.
__launch_bounds__(256)
__global__ void k_xproj(const float* __restrict__ xc, const float* __restrict__ xpw_t,
                        const float* __restrict__ dtw_t, const float* __restrict__ dtb,
                        float* __restrict__ delta, float* __restrict__ bc) {
  __shared__ float As[16][68];
  __shared__ float Bs[16][64];
  __shared__ float xd[24][68];
  __shared__ float Dtw[24][192];
  const int t = threadIdx.x;
  const int m0 = blockIdx.x * 64;
  const int s = m0 >> 11, l0 = m0 & 2047;
  for (int i = t; i < 24 * 192; i += 256) Dtw[i / 192][i % 192] = dtw_t[i];
  const int tx = t & 15, ty = t >> 4;
  const int lk = t >> 4, mq = t & 15;
  float acc[4][4];
#pragma unroll
  for (int i = 0; i < 4; ++i)
#pragma unroll
    for (int j = 0; j < 4; ++j) acc[i][j] = 0.0f;

  for (int k0 = 0; k0 < 192; k0 += 16) {
    const float4 a = *(const float4*)&xc[((size_t)s * 192 + k0 + lk) * 2048 + l0 + mq * 4];
    float4 b;
    if (mq < 14) b = *(const float4*)&xpw_t[(size_t)(k0 + lk) * 56 + mq * 4];
    else         b = make_float4(0.f, 0.f, 0.f, 0.f);
    __syncthreads();
    *(float4*)&As[lk][mq * 4] = a;
    *(float4*)&Bs[lk][mq * 4] = b;
    __syncthreads();
#pragma unroll
    for (int k = 0; k < 16; ++k) {
      const float4 av = *(const float4*)&As[k][tx * 4];
      const float4 bv = *(const float4*)&Bs[k][ty * 4];
      const float a4[4] = {av.x, av.y, av.z, av.w};
      const float b4[4] = {bv.x, bv.y, bv.z, bv.w};
#pragma unroll
      for (int i = 0; i < 4; ++i)
#pragma unroll
        for (int j = 0; j < 4; ++j) acc[i][j] = fmaf(a4[i], b4[j], acc[i][j]);
    }
  }
  const int nbase = ty * 4;
  if (nbase < 24) {
#pragma unroll
    for (int j = 0; j < 4; ++j)
#pragma unroll
      for (int i = 0; i < 4; ++i) xd[nbase + j][tx * 4 + i] = acc[i][j];
  } else if (nbase < 56) {
#pragma unroll
    for (int i = 0; i < 4; ++i) {
      float4 v; v.x = acc[i][0]; v.y = acc[i][1]; v.z = acc[i][2]; v.w = acc[i][3];
      *(float4*)&bc[(size_t)(m0 + tx * 4 + i) * 32 + (nbase - 24)] = v;
    }
  }
  __syncthreads();
#pragma unroll
  for (int dc = 0; dc < 3; ++dc) {
    float a2[4][4];
#pragma unroll
    for (int i = 0; i < 4; ++i)
#pragma unroll
      for (int j = 0; j < 4; ++j) a2[i][j] = 0.0f;
    const int d0 = dc * 64 + ty * 4;
#pragma unroll
    for (int r = 0; r < 24; ++r) {
      const float4 av = *(const float4*)&xd[r][tx * 4];
      const float4 bv = *(const float4*)&Dtw[r][d0];
      const float a4[4] = {av.x, av.y, av.z, av.w};
      const float b4[4] = {bv.x, bv.y, bv.z, bv.w};
#pragma unroll
      for (int i = 0; i < 4; ++i)
#pragma unroll
        for (int j = 0; j < 4; ++j) a2[i][j] = fmaf(a4[i], b4[j], a2[i][j]);
    }
#pragma unroll
    for (int j = 0; j < 4; ++j) {
      const int d = d0 + j;
      const float bb = dtb[d];
      float4 v;
      v.x = softplusf(a2[0][j] + bb);
      v.y = softplusf(a2[1][j] + bb);
      v.z = softplusf(a2[2][j] + bb);
      v.w = softplusf(a2[3][j] + bb);
      *(float4*)&delta[((size_t)s * 192 + d) * 2048 + l0 + tx * 4] = v;
    }
  }
}

// ---------------------------------------------------------------------------
// Scan carries layout: idx = ((sd2*NCHK + tc)*192 + d)*16 + n, sd2 = s*2+dir.
// scanA: per-chunk gain G = prod(dA) and zero-init end state hend.
__launch_bounds__(256)
__global__ void k_scanA(const float* __restrict__ delta, const float* __restrict__ xc,
                        const float* __restrict__ bc, const float* __restrict__ A_log,
                        const float* __restrict__ Ab_log,
                        float* __restrict__ G, float* __restrict__ hc) {
  __shared__ float dch[16][CLEN + 4];
  __shared__ float uch[16][CLEN + 4];
  __shared__ float bs[CLEN][16];
  const int t = threadIdx.x;
  const int dl = t >> 4, n = t & 15;
  const int dg = blockIdx.x;        // 0..11 channel group
  const int s  = blockIdx.y;        // 0..11
  const int z  = blockIdx.z;        // dir*NCHK + tc
  const int dir = z >> 4, tc = z & 15;
  const int d = dg * 16 + dl;
  const int base_l = dir ? (LQ - CLEN * (tc + 1)) : (CLEN * tc);
  const float a = -__expf((dir ? Ab_log : A_log)[d * 16 + n]);

  // stage delta/u: 16 rows x 128 floats = 512 float4, 2 per thread
  {
    const size_t rb = ((size_t)s * 192 + dg * 16) * 2048 + base_l;
#pragma unroll
    for (int it = 0; it < 2; ++it) {
      const int i = t + it * 256;
      const int row = i >> 5, c4 = (i & 31) * 4;
      const float4 dv = *(const float4*)&delta[rb + (size_t)row * 2048 + c4];
      const float4 uv = *(const float4*)&xc[rb + (size_t)row * 2048 + c4];
      *(float4*)&dch[row][c4] = dv;
      *(float4*)&uch[row][c4] = uv;
    }
    // stage B: 128 l x 16 n = 512 float4 (cols 0..15 of bc), 2 per thread
    const size_t bb = ((size_t)s * 2048 + base_l) * 32;
#pragma unroll
    for (int it = 0; it < 2; ++it) {
      const int i = t + it * 256;
      const int l = i >> 2, nq = (i & 3) * 4;
      *(float4*)&bs[l][nq] = *(const float4*)&bc[bb + (size_t)l * 32 + nq];
    }
  }
  __syncthreads();
  float h = 0.0f, P = 1.0f;
#pragma unroll 8
  for (int q = 0; q < CLEN; ++q) {
    const int lq = dir ? (CLEN - 1 - q) : q;
    const float dlt = dch[dl][lq];
    const float u = uch[dl][lq];
    const float bn = bs[lq][n];
    const float dA = __expf(dlt * a);
    h = fmaf(dA, h, dlt * u * bn);
    P *= dA;
  }
  const size_t idx = (((size_t)(s * 2 + dir) * NCHK + tc) * 192 + d) * 16 + n;
  G[idx] = P;
  hc[idx] = h;
}

// scanB: sequential carry scan over chunks; hc[tc] := h_in(tc) (in place).
__global__ void k_scanB(const float* __restrict__ G, float* __restrict__ hc) {
  const int gid = blockIdx.x * 256 + threadIdx.x;   // ((s*2+dir)*192+d)*16+n
  const int sd2 = gid / 3072;
  const int dn = gid % 3072;
  float h = 0.0f;
#pragma unroll
  for (int tc = 0; tc < NCHK; ++tc) {
    const size_t idx = ((size_t)sd2 * NCHK + tc) * 3072 + dn;
    const float g = G[idx];
    const float he = hc[idx];
    hc[idx] = h;
    h = fmaf(g, h, he);
  }
}

// scanC: re-run chunk seeded with h_in, emit y (reduce over n via shfl).
__launch_bounds__(256)
__global__ void k_scanC(const float* __restrict__ delta, const float* __restrict__ xc,
                        const float* __restrict__ bc, const float* __restrict__ A_log,
                        const float* __restrict__ Ab_log, const float* __restrict__ hc,
                        float* __restrict__ yf, float* __restrict__ yb) {
  __shared__ float dch[16][CLEN + 4];
  __shared__ float uch[16][CLEN + 4];
  __shared__ float bcs[CLEN][32];
  __shared__ float ys[16][CLEN + 4];
  const int t = threadIdx.x;
  const int dl = t >> 4, n = t & 15;
  const int dg = blockIdx.x;
  const int s  = blockIdx.y;
  const int z  = blockIdx.z;
  const int dir = z >> 4, tc = z & 15;
  const int d = dg * 16 + dl;
  const int base_l = dir ? (LQ - CLEN * (tc + 1)) : (CLEN * tc);
  const float a = -__expf((dir ? Ab_log : A_log)[d * 16 + n]);

  {
    const size_t rb = ((size_t)s * 192 + dg * 16) * 2048 + base_l;
#pragma unroll
    for (int it = 0; it < 2; ++it) {
      const int i = t + it * 256;
      const int row = i >> 5, c4 = (i & 31) * 4;
      const float4 dv = *(const float4*)&delta[rb + (size_t)row * 2048 + c4];
      const float4 uv = *(const float4*)&xc[rb + (size_t)row * 2048 + c4];
      *(float4*)&dch[row][c4] = dv;
      *(float4*)&uch[row][c4] = uv;
    }
    const size_t bb = ((size_t)s * 2048 + base_l) * 32;
#pragma unroll
    for (int it = 0; it < 4; ++it) {
      const int i = t + it * 256;
      const int l = i >> 3, nq = (i & 7) * 4;
      *(float4*)&bcs[l][nq] = *(const float4*)&bc[bb + (size_t)l * 32 + nq];
    }
  }
  const size_t idx = (((size_t)(s * 2 + dir) * NCHK + tc) * 192 + d) * 16 + n;
  float h = hc[idx];
  __syncthreads();
#pragma unroll 8
  for (int q = 0; q < CLEN; ++q) {
    const int lq = dir ? (CLEN - 1 - q) : q;
    const float dlt = dch[dl][lq];
    const float u = uch[dl][lq];
    const float bn = bcs[lq][n];
    const float cn = bcs[lq][16 + n];
    const float dA = __expf(dlt * a);
    h = fmaf(dA, h, dlt * u * bn);
    float yv = h * cn;
    yv += __shfl_xor(yv, 1);
    yv += __shfl_xor(yv, 2);
    yv += __shfl_xor(yv, 4);
    yv += __shfl_xor(yv, 8);
    if (n == 0) ys[dl][lq] = yv;
  }
  __syncthreads();
  float* yrow = &(dir ? yb : yf)[((size_t)s * 192 + d) * 2048 + base_l];
#pragma unroll
  for (int it = 0; it < 2; ++it) {
    const int j = n * 8 + it * 4;
    const float4 v = *(const float4*)&ys[dl][j];
    *(float4*)&yrow[j] = v;
  }
}

// ---------------------------------------------------------------------------
// K5: out_proj GEMM with fused concat.
__launch_bounds__(256)
__global__ void k_outproj(const float* __restrict__ yf, const float* __restrict__ yb,
                          const float* __restrict__ xc, const float* __restrict__ Dvec,
                          const float* __restrict__ w, const float* __restrict__ bias,
                          float* __restrict__ out) {
  __shared__ float As[16][132];
  __shared__ float Bs[16][68];
  const int t = threadIdx.x;
  const int m0 = blockIdx.x * 128;
  const int n0 = blockIdx.y * 64;
  const int s = m0 >> 11, l0 = m0 & 2047;
  const int tx = t & 31, ty = t >> 5;
  const int ck = t >> 4, mq = t & 15;
  const int nl = t >> 2, kq = t & 3;
  float acc[4][8];
#pragma unroll
  for (int i = 0; i < 4; ++i)
#pragma unroll
    for (int j = 0; j < 8; ++j) acc[i][j] = 0.0f;

  for (int k0 = 0; k0 < 384; k0 += 16) {
    const int c = k0 + ck;
    float4 av0, av1;
    if (c < 192) {
      const size_t off = ((size_t)s * 192 + c) * 2048 + l0;
      const float dv2 = 2.0f * Dvec[c];
      const float4 f0 = *(const float4*)&yf[off + mq * 4];
      const float4 g0 = *(const float4*)&yb[off + mq * 4];
      const float4 u0 = *(const float4*)&xc[off + mq * 4];
      av0.x = f0.x + g0.x + dv2 * u0.x; av0.y = f0.y + g0.y + dv2 * u0.y;
      av0.z = f0.z + g0.z + dv2 * u0.z; av0.w = f0.w + g0.w + dv2 * u0.w;
      const float4 f1 = *(const float4*)&yf[off + (mq + 16) * 4];
      const float4 g1 = *(const float4*)&yb[off + (mq + 16) * 4];
      const float4 u1 = *(const float4*)&xc[off + (mq + 16) * 4];
      av1.x = f1.x + g1.x + dv2 * u1.x; av1.y = f1.y + g1.y + dv2 * u1.y;
      av1.z = f1.z + g1.z + dv2 * u1.z; av1.w = f1.w + g1.w + dv2 * u1.w;
    } else {
      const size_t off = ((size_t)s * 192 + (c - 192)) * 2048 + l0;
      av0 = *(const float4*)&xc[off + mq * 4];
      av1 = *(const float4*)&xc[off + (mq + 16) * 4];
    }
    const float4 b0 = *(const float4*)&w[(size_t)(n0 + nl) * 384 + k0 + kq * 4];
    __syncthreads();
    *(float4*)&As[ck][mq * 4] = av0;
    *(float4*)&As[ck][(mq + 16) * 4] = av1;
    Bs[kq * 4 + 0][nl] = b0.x; Bs[kq * 4 + 1][nl] = b0.y;
    Bs[kq * 4 + 2][nl] = b0.z; Bs[kq * 4 + 3][nl] = b0.w;
    __syncthreads();
#pragma unroll
    for (int k = 0; k < 16; ++k) {
      const float4 av  = *(const float4*)&As[k][tx * 4];
      const float4 bv0 = *(const float4*)&Bs[k][ty * 8];
      const float4 bv1 = *(const float4*)&Bs[k][ty * 8 + 4];
      const float a4[4] = {av.x, av.y, av.z, av.w};
      const float b8[8] = {bv0.x, bv0.y, bv0.z, bv0.w, bv1.x, bv1.y, bv1.z, bv1.w};
#pragma unroll
      for (int i = 0; i < 4; ++i)
#pragma unroll
        for (int j = 0; j < 8; ++j) acc[i][j] = fmaf(a4[i], b8[j], acc[i][j]);
    }
  }
  const float4 bb0 = *(const float4*)&bias[n0 + ty * 8];
  const float4 bb1 = *(const float4*)&bias[n0 + ty * 8 + 4];
#pragma unroll
  for (int i = 0; i < 4; ++i) {
    float4 v0, v1;
    v0.x = acc[i][0] + bb0.x; v0.y = acc[i][1] + bb0.y;
    v0.z = acc[i][2] + bb0.z; v0.w = acc[i][3] + bb0.w;
    v1.x = acc[i][4] + bb1.x; v1.y = acc[i][5] + bb1.y;
    v1.z = acc[i][6] + bb1.z; v1.w = acc[i][7] + bb1.w;
    const size_t ro = (size_t)(m0 + tx * 4 + i) * 384 + n0 + ty * 8;
    *(float4*)&out[ro] = v0;
    *(float4*)&out[ro + 4] = v1;
  }
}

// ---------------------------------------------------------------------------
extern "C" void kernel_launch(void* const* d_in, const int* in_sizes, int n_in,
                              void* d_out, int out_size, void* d_ws, size_t ws_size,
                              hipStream_t stream) {
  const float* x     = (const float*)d_in[0];
  const float* inw   = (const float*)d_in[1];
  const float* inb   = (const float*)d_in[2];
  const float* convw = (const float*)d_in[3];
  const float* convb = (const float*)d_in[4];
  const float* alog  = (const float*)d_in[5];
  const float* ablog = (const float*)d_in[6];
  const float* Dv    = (const float*)d_in[7];
  const float* xpw   = (const float*)d_in[8];
  const float* dtw   = (const float*)d_in[9];
  const float* dtb   = (const float*)d_in[10];
  const float* outw  = (const float*)d_in[11];
  const float* outb  = (const float*)d_in[12];
  float* out = (float*)d_out;

  float* ws = (float*)d_ws;
  float* xp_t  = ws;                       // 9437184
  float* xc    = xp_t + 9437184;           // 4718592
  float* delta = xc + 4718592;             // 4718592
  float* bc    = delta + 4718592;          // 786432
  float* xpw_t = bc + 786432;              // 10752
  float* dtw_t = xpw_t + 10752;            // 4608
  float* G     = dtw_t + 4608;             // 1179648 (12s*2dir*16tc*192d*16n)
  float* hc    = G + 1179648;              // 1179648
  // yf/yb alias xp_t (dead after conv)
  float* yf = xp_t;
  float* yb = xp_t + 4718592;

  hipLaunchKernelGGL(k_prep,    dim3(8),          dim3(256), 0, stream, xpw, dtw, xpw_t, dtw_t);
  hipLaunchKernelGGL(k_inproj,  dim3(192, 6),     dim3(256), 0, stream, x, inw, inb, xp_t);
  hipLaunchKernelGGL(k_conv,    dim3(18432),      dim3(256), 0, stream, xp_t, convw, convb, xc);
  hipLaunchKernelGGL(k_xproj,   dim3(384),        dim3(256), 0, stream, xc, xpw_t, dtw_t, dtb, delta, bc);
  hipLaunchKernelGGL(k_scanA,   dim3(12, 12, 32), dim3(256), 0, stream, delta, xc, bc, alog, ablog, G, hc);
  hipLaunchKernelGGL(k_scanB,   dim3(288),        dim3(256), 0, stream, G, hc);
  hipLaunchKernelGGL(k_scanC,   dim3(12, 12, 32), dim3(256), 0, stream, delta, xc, bc, alog, ablog, hc, yf, yb);
  hipLaunchKernelGGL(k_outproj, dim3(192, 6),     dim3(256), 0, stream, yf, yb, xc, Dv, outw, outb, out);
}

// Round 4
// 499.153 us; speedup vs baseline: 2.3549x; 1.1956x over previous
//
#include <hip/hip_runtime.h>
#include <hip/hip_bf16.h>
#include <math.h>

// Problem constants
#define NSQ   12      // b*F sequences
#define LQ    2048    // per-sequence length
#define DIMQ  384
#define DIQ   192     // d_in
#define RKQ   24      // dt rank
#define NCHK  16      // scan chunks
#define CLEN  128     // chunk length (LQ/NCHK)

__device__ __forceinline__ float siluf(float x) {
  return x / (1.0f + __expf(-x));
}
__device__ __forceinline__ float softplusf(float x) {
  return (x > 20.0f) ? x : log1pf(expf(x));
}

union F4 { float4 v; float a[4]; };

// VALU-only 16-lane rotation-add (DPP row_ror). All lanes end with the sum.
template<int CTRL>
__device__ __forceinline__ float dpp_add(float x) {
  union { float f; int i; } u, r;
  u.f = x;
  r.i = __builtin_amdgcn_update_dpp(0, u.i, CTRL, 0xF, 0xF, true);
  return x + r.f;
}

// ---------------------------------------------------------------------------
// K0: transpose small weight matrices for coalesced access later.
__global__ void k_prep(const float* __restrict__ xpw, const float* __restrict__ dtw,
                       float* __restrict__ xpw_t, float* __restrict__ dtw_t) {
  int t = threadIdx.x + blockIdx.x * blockDim.x;
  int stride = blockDim.x * gridDim.x;
  for (int i = t; i < DIQ * 56; i += stride) {
    int d = i / 56, r = i % 56;
    xpw_t[i] = xpw[r * DIQ + d];
  }
  for (int i = t; i < RKQ * DIQ; i += stride) {
    int r = i / DIQ, d = i % DIQ;
    dtw_t[i] = dtw[d * RKQ + r];
  }
}

// ---------------------------------------------------------------------------
// K1: in_proj GEMM, output channel-major xp_t[(s*384+c)*2048 + p].
__launch_bounds__(256)
__global__ void k_inproj(const float* __restrict__ x, const float* __restrict__ w,
                         const float* __restrict__ bias, float* __restrict__ xp_t) {
  __shared__ float As[16][132];
  __shared__ float Bs[16][68];
  const int t = threadIdx.x;
  const int m0 = blockIdx.x * 128;
  const int n0 = blockIdx.y * 64;
  const int tx = t & 31, ty = t >> 5;
  const int ml = t >> 2, kq = t & 3;
  float acc[4][8];
#pragma unroll
  for (int i = 0; i < 4; ++i)
#pragma unroll
    for (int j = 0; j < 8; ++j) acc[i][j] = 0.0f;

  for (int k0 = 0; k0 < 384; k0 += 16) {
    const float4 a0 = *(const float4*)&x[(size_t)(m0 + ml) * 384 + k0 + kq * 4];
    const float4 a1 = *(const float4*)&x[(size_t)(m0 + ml + 64) * 384 + k0 + kq * 4];
    const float4 b0 = *(const float4*)&w[(size_t)(n0 + ml) * 384 + k0 + kq * 4];
    __syncthreads();
    As[kq * 4 + 0][ml] = a0.x; As[kq * 4 + 1][ml] = a0.y;
    As[kq * 4 + 2][ml] = a0.z; As[kq * 4 + 3][ml] = a0.w;
    As[kq * 4 + 0][ml + 64] = a1.x; As[kq * 4 + 1][ml + 64] = a1.y;
    As[kq * 4 + 2][ml + 64] = a1.z; As[kq * 4 + 3][ml + 64] = a1.w;
    Bs[kq * 4 + 0][ml] = b0.x; Bs[kq * 4 + 1][ml] = b0.y;
    Bs[kq * 4 + 2][ml] = b0.z; Bs[kq * 4 + 3][ml] = b0.w;
    __syncthreads();
#pragma unroll
    for (int k = 0; k < 16; ++k) {
      const float4 av  = *(const float4*)&As[k][tx * 4];
      const float4 bv0 = *(const float4*)&Bs[k][ty * 8];
      const float4 bv1 = *(const float4*)&Bs[k][ty * 8 + 4];
      const float a4[4] = {av.x, av.y, av.z, av.w};
      const float b8[8] = {bv0.x, bv0.y, bv0.z, bv0.w, bv1.x, bv1.y, bv1.z, bv1.w};
#pragma unroll
      for (int i = 0; i < 4; ++i)
#pragma unroll
        for (int j = 0; j < 8; ++j) acc[i][j] = fmaf(a4[i], b8[j], acc[i][j]);
    }
  }
  const int s = m0 >> 11;
  const int p0 = m0 & 2047;
#pragma unroll
  for (int j = 0; j < 8; ++j) {
    const int c = n0 + ty * 8 + j;
    const float bv = bias[c];
    float4 v;
    v.x = acc[0][j] + bv; v.y = acc[1][j] + bv;
    v.z = acc[2][j] + bv; v.w = acc[3][j] + bv;
    *(float4*)&xp_t[((size_t)s * 384 + c) * 2048 + p0 + tx * 4] = v;
  }
}

// ---------------------------------------------------------------------------
// K2: grouped conv (k=3, SAME) + SiLU.
__global__ void k_conv(const float* __restrict__ xp_t, const float* __restrict__ cw,
                       const float* __restrict__ cb, float* __restrict__ xc) {
  const int idx = blockIdx.x * 256 + threadIdx.x;
  const int p = idx & 2047;
  const int sd = idx >> 11;
  const int d = sd % DIQ, s = sd / DIQ;
  const float* r0 = &xp_t[((size_t)s * 384 + 2 * d) * 2048];
  const float* r1 = r0 + 2048;
  const float w00 = cw[d * 6 + 0], w01 = cw[d * 6 + 1], w02 = cw[d * 6 + 2];
  const float w10 = cw[d * 6 + 3], w11 = cw[d * 6 + 4], w12 = cw[d * 6 + 5];
  float acc = cb[d];
  if (p > 0)    acc += w00 * r0[p - 1] + w10 * r1[p - 1];
  acc += w01 * r0[p] + w11 * r1[p];
  if (p < 2047) acc += w02 * r0[p + 1] + w12 * r1[p + 1];
  xc[idx] = siluf(acc);
}

// ---------------------------------------------------------------------------
// K3: fused x_proj + dt_proj + softplus.
__launch_bounds__(256)
__global__ void k_xproj(const float* __restrict__ xc, const float* __restrict__ xpw_t,
                        const float* __restrict__ dtw_t, const float* __restrict__ dtb,
                        float* __restrict__ delta, float* __restrict__ bc) {
  __shared__ float As[16][68];
  __shared__ float Bs[16][64];
  __shared__ float xd[24][68];
  __shared__ float Dtw[24][192];
  const int t = threadIdx.x;
  const int m0 = blockIdx.x * 64;
  const int s = m0 >> 11, l0 = m0 & 2047;
  for (int i = t; i < 24 * 192; i += 256) Dtw[i / 192][i % 192] = dtw_t[i];
  const int tx = t & 15, ty = t >> 4;
  const int lk = t >> 4, mq = t & 15;
  float acc[4][4];
#pragma unroll
  for (int i = 0; i < 4; ++i)
#pragma unroll
    for (int j = 0; j < 4; ++j) acc[i][j] = 0.0f;

  for (int k0 = 0; k0 < 192; k0 += 16) {
    const float4 a = *(const float4*)&xc[((size_t)s * 192 + k0 + lk) * 2048 + l0 + mq * 4];
    float4 b;
    if (mq < 14) b = *(const float4*)&xpw_t[(size_t)(k0 + lk) * 56 + mq * 4];
    else         b = make_float4(0.f, 0.f, 0.f, 0.f);
    __syncthreads();
    *(float4*)&As[lk][mq * 4] = a;
    *(float4*)&Bs[lk][mq * 4] = b;
    __syncthreads();
#pragma unroll
    for (int k = 0; k < 16; ++k) {
      const float4 av = *(const float4*)&As[k][tx * 4];
      const float4 bv = *(const float4*)&Bs[k][ty * 4];
      const float a4[4] = {av.x, av.y, av.z, av.w};
      const float b4[4] = {bv.x, bv.y, bv.z, bv.w};
#pragma unroll
      for (int i = 0; i < 4; ++i)
#pragma unroll
        for (int j = 0; j < 4; ++j) acc[i][j] = fmaf(a4[i], b4[j], acc[i][j]);
    }
  }
  const int nbase = ty * 4;
  if (nbase < 24) {
#pragma unroll
    for (int j = 0; j < 4; ++j)
#pragma unroll
      for (int i = 0; i < 4; ++i) xd[nbase + j][tx * 4 + i] = acc[i][j];
  } else if (nbase < 56) {
#pragma unroll
    for (int i = 0; i < 4; ++i) {
      float4 v; v.x = acc[i][0]; v.y = acc[i][1]; v.z = acc[i][2]; v.w = acc[i][3];
      *(float4*)&bc[(size_t)(m0 + tx * 4 + i) * 32 + (nbase - 24)] = v;
    }
  }
  __syncthreads();
#pragma unroll
  for (int dc = 0; dc < 3; ++dc) {
    float a2[4][4];
#pragma unroll
    for (int i = 0; i < 4; ++i)
#pragma unroll
      for (int j = 0; j < 4; ++j) a2[i][j] = 0.0f;
    const int d0 = dc * 64 + ty * 4;
#pragma unroll
    for (int r = 0; r < 24; ++r) {
      const float4 av = *(const float4*)&xd[r][tx * 4];
      const float4 bv = *(const float4*)&Dtw[r][d0];
      const float a4[4] = {av.x, av.y, av.z, av.w};
      const float b4[4] = {bv.x, bv.y, bv.z, bv.w};
#pragma unroll
      for (int i = 0; i < 4; ++i)
#pragma unroll
        for (int j = 0; j < 4; ++j) a2[i][j] = fmaf(a4[i], b4[j], a2[i][j]);
    }
#pragma unroll
    for (int j = 0; j < 4; ++j) {
      const int d = d0 + j;
      const float bb = dtb[d];
      float4 v;
      v.x = softplusf(a2[0][j] + bb);
      v.y = softplusf(a2[1][j] + bb);
      v.z = softplusf(a2[2][j] + bb);
      v.w = softplusf(a2[3][j] + bb);
      *(float4*)&delta[((size_t)s * 192 + d) * 2048 + l0 + tx * 4] = v;
    }
  }
}

// ---------------------------------------------------------------------------
// Scan carries layout: idx = ((sd2*NCHK + tc)*192 + d)*16 + n, sd2 = s*2+dir.
// scanA: per-chunk gain G = exp(a*sum(delta)) and zero-init end state hend.
template<int DIR>
__launch_bounds__(256)
__global__ void k_scanA(const float* __restrict__ delta, const float* __restrict__ xc,
                        const float* __restrict__ bc, const float* __restrict__ A_log,
                        const float* __restrict__ Ab_log,
                        float* __restrict__ G, float* __restrict__ hc) {
  __shared__ float dch[16][132];
  __shared__ float uch[16][132];
  __shared__ float bsn[16][132];   // B transposed: [n][l]
  const int t = threadIdx.x;
  const int dl = t >> 4, n = t & 15;
  const int dg = blockIdx.x;        // 0..11 channel group
  const int s  = blockIdx.y;        // 0..11
  const int tc = blockIdx.z;        // 0..15 chunk
  const int d = dg * 16 + dl;
  const int base_l = DIR ? (LQ - CLEN * (tc + 1)) : (CLEN * tc);
  const float a = -__expf((DIR ? Ab_log : A_log)[d * 16 + n]);

  const size_t rb = ((size_t)s * 192 + dg * 16) * 2048 + base_l;
#pragma unroll
  for (int it = 0; it < 2; ++it) {
    const int i = t + it * 256;
    const int row = i >> 5, c4 = (i & 31) * 4;
    *(float4*)&dch[row][c4] = *(const float4*)&delta[rb + (size_t)row * 2048 + c4];
    *(float4*)&uch[row][c4] = *(const float4*)&xc[rb + (size_t)row * 2048 + c4];
  }
  const size_t bb = ((size_t)s * 2048 + base_l) * 32;
#pragma unroll
  for (int it = 0; it < 2; ++it) {
    const int i = t + it * 256;
    const int l = i >> 2, nq = (i & 3) * 4;
    F4 v; v.v = *(const float4*)&bc[bb + (size_t)l * 32 + nq];
#pragma unroll
    for (int k = 0; k < 4; ++k) bsn[nq + k][l] = v.a[k];
  }
  __syncthreads();
  float h = 0.0f, S = 0.0f;
#pragma unroll 4
  for (int qx = 0; qx < 32; ++qx) {
    const int q = DIR ? (31 - qx) : qx;
    const int lq = q * 4;
    F4 d4, u4, b4;
    d4.v = *(const float4*)&dch[dl][lq];
    u4.v = *(const float4*)&uch[dl][lq];
    b4.v = *(const float4*)&bsn[n][lq];
#pragma unroll
    for (int jj = 0; jj < 4; ++jj) {
      const int j = DIR ? (3 - jj) : jj;
      const float dlt = d4.a[j];
      const float dA = __expf(a * dlt);
      h = fmaf(dA, h, dlt * u4.a[j] * b4.a[j]);
      S += dlt;
    }
  }
  const size_t idx = (((size_t)(s * 2 + DIR) * NCHK + tc) * 192 + d) * 16 + n;
  G[idx] = __expf(a * S);
  hc[idx] = h;
}

// scanB: sequential carry scan over chunks; hc[tc] := h_in(tc) (in place).
__global__ void k_scanB(const float* __restrict__ G, float* __restrict__ hc) {
  const int gid = blockIdx.x * 256 + threadIdx.x;   // ((s*2+dir)*192+d)*16+n
  const int sd2 = gid / 3072;
  const int dn = gid % 3072;
  float h = 0.0f;
#pragma unroll
  for (int tc = 0; tc < NCHK; ++tc) {
    const size_t idx = ((size_t)sd2 * NCHK + tc) * 3072 + dn;
    const float g = G[idx];
    const float he = hc[idx];
    hc[idx] = h;
    h = fmaf(g, h, he);
  }
}

// scanC: re-run chunk seeded with h_in, emit y. DPP rotation reduce over 16 n
// lanes (all lanes get the sum); lane n retains step l where (l&15)==n and
// stores one float per 16-step window (coalesced 64B groups).
template<int DIR>
__launch_bounds__(256)
__global__ void k_scanC(const float* __restrict__ delta, const float* __restrict__ xc,
                        const float* __restrict__ bc, const float* __restrict__ A_log,
                        const float* __restrict__ Ab_log, const float* __restrict__ hc,
                        float* __restrict__ yf, float* __restrict__ yb) {
  __shared__ float dch[16][132];
  __shared__ float uch[16][132];
  __shared__ float bsn[16][132];   // B transposed [n][l]
  __shared__ float csn[16][132];   // C transposed [n][l]
  const int t = threadIdx.x;
  const int dl = t >> 4, n = t & 15;
  const int dg = blockIdx.x;
  const int s  = blockIdx.y;
  const int tc = blockIdx.z;
  const int d = dg * 16 + dl;
  const int base_l = DIR ? (LQ - CLEN * (tc + 1)) : (CLEN * tc);
  const float a = -__expf((DIR ? Ab_log : A_log)[d * 16 + n]);

  const size_t rb = ((size_t)s * 192 + dg * 16) * 2048 + base_l;
#pragma unroll
  for (int it = 0; it < 2; ++it) {
    const int i = t + it * 256;
    const int row = i >> 5, c4 = (i & 31) * 4;
    *(float4*)&dch[row][c4] = *(const float4*)&delta[rb + (size_t)row * 2048 + c4];
    *(float4*)&uch[row][c4] = *(const float4*)&xc[rb + (size_t)row * 2048 + c4];
  }
  const size_t bb = ((size_t)s * 2048 + base_l) * 32;
#pragma unroll
  for (int it = 0; it < 4; ++it) {
    const int i = t + it * 256;
    const int l = i >> 3, cq = (i & 7) * 4;
    F4 v; v.v = *(const float4*)&bc[bb + (size_t)l * 32 + cq];
    if (cq < 16) {
#pragma unroll
      for (int k = 0; k < 4; ++k) bsn[cq + k][l] = v.a[k];
    } else {
#pragma unroll
      for (int k = 0; k < 4; ++k) csn[cq - 16 + k][l] = v.a[k];
    }
  }
  const size_t idx = (((size_t)(s * 2 + DIR) * NCHK + tc) * 192 + d) * 16 + n;
  float h = hc[idx];
  __syncthreads();
  float* yrow = &(DIR ? yb : yf)[((size_t)s * 192 + d) * 2048 + base_l];
#pragma unroll 2
  for (int ww = 0; ww < 8; ++ww) {
    const int w = DIR ? (7 - ww) : ww;
    float ykeep = 0.0f;
#pragma unroll
    for (int qq = 0; qq < 4; ++qq) {
      const int q = DIR ? (3 - qq) : qq;
      const int lq = w * 16 + q * 4;
      F4 d4, u4, b4, c4;
      d4.v = *(const float4*)&dch[dl][lq];
      u4.v = *(const float4*)&uch[dl][lq];
      b4.v = *(const float4*)&bsn[n][lq];
      c4.v = *(const float4*)&csn[n][lq];
#pragma unroll
      for (int jj = 0; jj < 4; ++jj) {
        const int j = DIR ? (3 - jj) : jj;
        const float dlt = d4.a[j];
        const float dA = __expf(a * dlt);
        h = fmaf(dA, h, dlt * u4.a[j] * b4.a[j]);
        float yv = h * c4.a[j];
        yv = dpp_add<0x128>(yv);   // row_ror:8
        yv = dpp_add<0x124>(yv);   // row_ror:4
        yv = dpp_add<0x122>(yv);   // row_ror:2
        yv = dpp_add<0x121>(yv);   // row_ror:1
        ykeep = (q * 4 + j == n) ? yv : ykeep;
      }
    }
    yrow[w * 16 + n] = ykeep;
  }
}

// ---------------------------------------------------------------------------
// K5: out_proj GEMM with fused concat.
__launch_bounds__(256)
__global__ void k_outproj(const float* __restrict__ yf, const float* __restrict__ yb,
                          const float* __restrict__ xc, const float* __restrict__ Dvec,
                          const float* __restrict__ w, const float* __restrict__ bias,
                          float* __restrict__ out) {
  __shared__ float As[16][132];
  __shared__ float Bs[16][68];
  const int t = threadIdx.x;
  const int m0 = blockIdx.x * 128;
  const int n0 = blockIdx.y * 64;
  const int s = m0 >> 11, l0 = m0 & 2047;
  const int tx = t & 31, ty = t >> 5;
  const int ck = t >> 4, mq = t & 15;
  const int nl = t >> 2, kq = t & 3;
  float acc[4][8];
#pragma unroll
  for (int i = 0; i < 4; ++i)
#pragma unroll
    for (int j = 0; j < 8; ++j) acc[i][j] = 0.0f;

  for (int k0 = 0; k0 < 384; k0 += 16) {
    const int c = k0 + ck;
    float4 av0, av1;
    if (c < 192) {
      const size_t off = ((size_t)s * 192 + c) * 2048 + l0;
      const float dv2 = 2.0f * Dvec[c];
      const float4 f0 = *(const float4*)&yf[off + mq * 4];
      const float4 g0 = *(const float4*)&yb[off + mq * 4];
      const float4 u0 = *(const float4*)&xc[off + mq * 4];
      av0.x = f0.x + g0.x + dv2 * u0.x; av0.y = f0.y + g0.y + dv2 * u0.y;
      av0.z = f0.z + g0.z + dv2 * u0.z; av0.w = f0.w + g0.w + dv2 * u0.w;
      const float4 f1 = *(const float4*)&yf[off + (mq + 16) * 4];
      const float4 g1 = *(const float4*)&yb[off + (mq + 16) * 4];
      const float4 u1 = *(const float4*)&xc[off + (mq + 16) * 4];
      av1.x = f1.x + g1.x + dv2 * u1.x; av1.y = f1.y + g1.y + dv2 * u1.y;
      av1.z = f1.z + g1.z + dv2 * u1.z; av1.w = f1.w + g1.w + dv2 * u1.w;
    } else {
      const size_t off = ((size_t)s * 192 + (c - 192)) * 2048 + l0;
      av0 = *(const float4*)&xc[off + mq * 4];
      av1 = *(const float4*)&xc[off + (mq + 16) * 4];
    }
    const float4 b0 = *(const float4*)&w[(size_t)(n0 + nl) * 384 + k0 + kq * 4];
    __syncthreads();
    *(float4*)&As[ck][mq * 4] = av0;
    *(float4*)&As[ck][(mq + 16) * 4] = av1;
    Bs[kq * 4 + 0][nl] = b0.x; Bs[kq * 4 + 1][nl] = b0.y;
    Bs[kq * 4 + 2][nl] = b0.z; Bs[kq * 4 + 3][nl] = b0.w;
    __syncthreads();
#pragma unroll
    for (int k = 0; k < 16; ++k) {
      const float4 av  = *(const float4*)&As[k][tx * 4];
      const float4 bv0 = *(const float4*)&Bs[k][ty * 8];
      const float4 bv1 = *(const float4*)&Bs[k][ty * 8 + 4];
      const float a4[4] = {av.x, av.y, av.z, av.w};
      const float b8[8] = {bv0.x, bv0.y, bv0.z, bv0.w, bv1.x, bv1.y, bv1.z, bv1.w};
#pragma unroll
      for (int i = 0; i < 4; ++i)
#pragma unroll
        for (int j = 0; j < 8; ++j) acc[i][j] = fmaf(a4[i], b8[j], acc[i][j]);
    }
  }
  const float4 bb0 = *(const float4*)&bias[n0 + ty * 8];
  const float4 bb1 = *(const float4*)&bias[n0 + ty * 8 + 4];
#pragma unroll
  for (int i = 0; i < 4; ++i) {
    float4 v0, v1;
    v0.x = acc[i][0] + bb0.x; v0.y = acc[i][1] + bb0.y;
    v0.z = acc[i][2] + bb0.z; v0.w = acc[i][3] + bb0.w;
    v1.x = acc[i][4] + bb1.x; v1.y = acc[i][5] + bb1.y;
    v1.z = acc[i][6] + bb1.z; v1.w = acc[i][7] + bb1.w;
    const size_t ro = (size_t)(m0 + tx * 4 + i) * 384 + n0 + ty * 8;
    *(float4*)&out[ro] = v0;
    *(float4*)&out[ro + 4] = v1;
  }
}

// ---------------------------------------------------------------------------
extern "C" void kernel_launch(void* const* d_in, const int* in_sizes, int n_in,
                              void* d_out, int out_size, void* d_ws, size_t ws_size,
                              hipStream_t stream) {
  const float* x     = (const float*)d_in[0];
  const float* inw   = (const float*)d_in[1];
  const float* inb   = (const float*)d_in[2];
  const float* convw = (const float*)d_in[3];
  const float* convb = (const float*)d_in[4];
  const float* alog  = (const float*)d_in[5];
  const float* ablog = (const float*)d_in[6];
  const float* Dv    = (const float*)d_in[7];
  const float* xpw   = (const float*)d_in[8];
  const float* dtw   = (const float*)d_in[9];
  const float* dtb   = (const float*)d_in[10];
  const float* outw  = (const float*)d_in[11];
  const float* outb  = (const float*)d_in[12];
  float* out = (float*)d_out;

  float* ws = (float*)d_ws;
  float* xp_t  = ws;                       // 9437184
  float* xc    = xp_t + 9437184;           // 4718592
  float* delta = xc + 4718592;             // 4718592
  float* bc    = delta + 4718592;          // 786432
  float* xpw_t = bc + 786432;              // 10752
  float* dtw_t = xpw_t + 10752;            // 4608
  float* G     = dtw_t + 4608;             // 1179648 (12s*2dir*16tc*192d*16n)
  float* hc    = G + 1179648;              // 1179648
  // yf/yb alias xp_t (dead after conv)
  float* yf = xp_t;
  float* yb = xp_t + 4718592;

  hipLaunchKernelGGL(k_prep,      dim3(8),          dim3(256), 0, stream, xpw, dtw, xpw_t, dtw_t);
  hipLaunchKernelGGL(k_inproj,    dim3(192, 6),     dim3(256), 0, stream, x, inw, inb, xp_t);
  hipLaunchKernelGGL(k_conv,      dim3(18432),      dim3(256), 0, stream, xp_t, convw, convb, xc);
  hipLaunchKernelGGL(k_xproj,     dim3(384),        dim3(256), 0, stream, xc, xpw_t, dtw_t, dtb, delta, bc);
  hipLaunchKernelGGL((k_scanA<0>),dim3(12, 12, 16), dim3(256), 0, stream, delta, xc, bc, alog, ablog, G, hc);
  hipLaunchKernelGGL((k_scanA<1>),dim3(12, 12, 16), dim3(256), 0, stream, delta, xc, bc, alog, ablog, G, hc);
  hipLaunchKernelGGL(k_scanB,     dim3(288),        dim3(256), 0, stream, G, hc);
  hipLaunchKernelGGL((k_scanC<0>),dim3(12, 12, 16), dim3(256), 0, stream, delta, xc, bc, alog, ablog, hc, yf, yb);
  hipLaunchKernelGGL((k_scanC<1>),dim3(12, 12, 16), dim3(256), 0, stream, delta, xc, bc, alog, ablog, hc, yf, yb);
  hipLaunchKernelGGL(k_outproj,   dim3(192, 6),     dim3(256), 0, stream, yf, yb, xc, Dv, outw, outb, out);
}

// Round 5
// 377.817 us; speedup vs baseline: 3.1112x; 1.3212x over previous
//
#include <hip/hip_runtime.h>
#include <hip/hip_bf16.h>
#include <math.h>

// Problem constants
#define NSQ   12      // b*F sequences
#define LQ    2048    // per-sequence length
#define DIMQ  384
#define DIQ   192     // d_in
#define RKQ   24      // dt rank
#define NCHK  16      // scan chunks
#define CLEN  128     // chunk length (LQ/NCHK)

// GEMM tiling
#define BM 128
#define BN 64
#define BK 64

typedef unsigned short u16;
typedef __attribute__((ext_vector_type(8))) short s16x8;
typedef __attribute__((ext_vector_type(4))) float f32x4;
typedef __attribute__((ext_vector_type(4))) unsigned short u16x4;
typedef __attribute__((ext_vector_type(8))) unsigned short u16x8;

__device__ __forceinline__ float siluf(float x) {
  return x / (1.0f + __expf(-x));
}
__device__ __forceinline__ float softplusf(float x) {
  return (x > 20.0f) ? x : log1pf(expf(x));
}
__device__ __forceinline__ u16 f2bf(float f) {   // RNE f32->bf16
  unsigned int u = __float_as_uint(f);
  u += 0x7FFFu + ((u >> 16) & 1u);
  return (u16)(u >> 16);
}

union F4 { float4 v; float a[4]; };

// VALU-only 16-lane rotation-add (DPP row_ror). All lanes end with the sum.
template<int CTRL>
__device__ __forceinline__ float dpp_add(float x) {
  union { float f; int i; } u, r;
  u.f = x;
  r.i = __builtin_amdgcn_update_dpp(0, u.i, CTRL, 0xF, 0xF, true);
  return x + r.f;
}

// ---------------------------------------------------------------------------
// K0: transpose small weights + convert big GEMM weights to bf16.
__global__ void k_prep(const float* __restrict__ xpw, const float* __restrict__ dtw,
                       const float* __restrict__ inw, const float* __restrict__ outw,
                       float* __restrict__ xpw_t, float* __restrict__ dtw_t,
                       u16* __restrict__ winb, u16* __restrict__ woutb) {
  int t = threadIdx.x + blockIdx.x * blockDim.x;
  int stride = blockDim.x * gridDim.x;
  for (int i = t; i < DIQ * 56; i += stride) {
    int d = i / 56, r = i % 56;
    xpw_t[i] = xpw[r * DIQ + d];
  }
  for (int i = t; i < RKQ * DIQ; i += stride) {
    int r = i / DIQ, d = i % DIQ;
    dtw_t[i] = dtw[d * RKQ + r];
  }
  for (int i = t; i < DIMQ * DIMQ; i += stride) {
    winb[i]  = f2bf(inw[i]);
    woutb[i] = f2bf(outw[i]);
  }
}

// ---------------------------------------------------------------------------
// K1: in_proj GEMM via MFMA bf16. A = x[m][384] (f32, converted inline),
// B rows = in_proj_w[c][k] (bf16). Output transposed to channel-major
// xp_t[(s*384+c)*2048 + p] via LDS epilogue.
__launch_bounds__(256)
__global__ void k_inproj(const float* __restrict__ x, const u16* __restrict__ wbf,
                         const float* __restrict__ bias, float* __restrict__ xp_t) {
  __shared__ __align__(16) char smem[33792];
  u16 (*As)[72] = (u16(*)[72])smem;                 // [128][72]
  u16 (*Bs)[72] = (u16(*)[72])(smem + 18432);       // [64][72]
  const int t = threadIdx.x;
  const int m0 = blockIdx.x * BM;
  const int n0 = blockIdx.y * BN;
  const int lane = t & 63, wid = t >> 6;
  const int wm = wid >> 1, wn = wid & 1;
  const int lr = lane & 15, lg = lane >> 4;
  f32x4 acc[4][2];
#pragma unroll
  for (int i = 0; i < 4; ++i)
#pragma unroll
    for (int j = 0; j < 2; ++j) acc[i][j] = (f32x4){0.f, 0.f, 0.f, 0.f};

  for (int k0 = 0; k0 < 384; k0 += BK) {
    float4 a_ld[8];
#pragma unroll
    for (int i = 0; i < 8; ++i) {
      const int idx = t + i * 256;                  // 2048
      const int row = idx >> 4, kq = (idx & 15) * 4;
      a_ld[i] = *(const float4*)&x[(size_t)(m0 + row) * 384 + k0 + kq];
    }
    u16x8 b_ld[2];
#pragma unroll
    for (int i = 0; i < 2; ++i) {
      const int idx = t + i * 256;                  // 512
      const int n = idx >> 3, kq = (idx & 7) * 8;
      b_ld[i] = *(const u16x8*)&wbf[(size_t)(n0 + n) * 384 + k0 + kq];
    }
    __syncthreads();
#pragma unroll
    for (int i = 0; i < 8; ++i) {
      const int idx = t + i * 256;
      const int row = idx >> 4, kq = (idx & 15) * 4;
      u16x4 p;
      p.x = f2bf(a_ld[i].x); p.y = f2bf(a_ld[i].y);
      p.z = f2bf(a_ld[i].z); p.w = f2bf(a_ld[i].w);
      *(u16x4*)&As[row][kq] = p;
    }
#pragma unroll
    for (int i = 0; i < 2; ++i) {
      const int idx = t + i * 256;
      const int n = idx >> 3, kq = (idx & 7) * 8;
      *(u16x8*)&Bs[n][kq] = b_ld[i];
    }
    __syncthreads();
#pragma unroll
    for (int kh = 0; kh < BK; kh += 32) {
      s16x8 af[4], bf[2];
#pragma unroll
      for (int mi = 0; mi < 4; ++mi)
        af[mi] = *(const s16x8*)&As[wm * 64 + mi * 16 + lr][kh + lg * 8];
#pragma unroll
      for (int ni = 0; ni < 2; ++ni)
        bf[ni] = *(const s16x8*)&Bs[wn * 32 + ni * 16 + lr][kh + lg * 8];
#pragma unroll
      for (int mi = 0; mi < 4; ++mi)
#pragma unroll
        for (int ni = 0; ni < 2; ++ni)
          acc[mi][ni] = __builtin_amdgcn_mfma_f32_16x16x32_bf16(af[mi], bf[ni], acc[mi][ni], 0, 0, 0);
    }
    __syncthreads();
  }
  // epilogue: transpose through LDS -> channel-major
  float (*T)[132] = (float(*)[132])smem;            // [64][132]
#pragma unroll
  for (int mi = 0; mi < 4; ++mi)
#pragma unroll
    for (int ni = 0; ni < 2; ++ni) {
      const int c_loc = wn * 32 + ni * 16 + lr;
      const int m_loc = wm * 64 + mi * 16 + lg * 4;
      *(f32x4*)&T[c_loc][m_loc] = acc[mi][ni];
    }
  __syncthreads();
  const int s = m0 >> 11, p0 = m0 & 2047;
#pragma unroll
  for (int i = 0; i < 8; ++i) {
    const int idx = t + i * 256;
    const int c = idx >> 5, pq = (idx & 31) * 4;
    float4 v = *(const float4*)&T[c][pq];
    const float bv = bias[n0 + c];
    v.x += bv; v.y += bv; v.z += bv; v.w += bv;
    *(float4*)&xp_t[((size_t)s * 384 + n0 + c) * 2048 + p0 + pq] = v;
  }
}

// ---------------------------------------------------------------------------
// K2: grouped conv (k=3, SAME) + SiLU.
__global__ void k_conv(const float* __restrict__ xp_t, const float* __restrict__ cw,
                       const float* __restrict__ cb, float* __restrict__ xc) {
  const int idx = blockIdx.x * 256 + threadIdx.x;
  const int p = idx & 2047;
  const int sd = idx >> 11;
  const int d = sd % DIQ, s = sd / DIQ;
  const float* r0 = &xp_t[((size_t)s * 384 + 2 * d) * 2048];
  const float* r1 = r0 + 2048;
  const float w00 = cw[d * 6 + 0], w01 = cw[d * 6 + 1], w02 = cw[d * 6 + 2];
  const float w10 = cw[d * 6 + 3], w11 = cw[d * 6 + 4], w12 = cw[d * 6 + 5];
  float acc = cb[d];
  if (p > 0)    acc += w00 * r0[p - 1] + w10 * r1[p - 1];
  acc += w01 * r0[p] + w11 * r1[p];
  if (p < 2047) acc += w02 * r0[p + 1] + w12 * r1[p + 1];
  xc[idx] = siluf(acc);
}

// ---------------------------------------------------------------------------
// K3: fused x_proj + dt_proj + softplus (f32 VALU, small).
__launch_bounds__(256)
__global__ void k_xproj(const float* __restrict__ xc, const float* __restrict__ xpw_t,
                        const float* __restrict__ dtw_t, const float* __restrict__ dtb,
                        float* __restrict__ delta, float* __restrict__ bc) {
  __shared__ float As[16][68];
  __shared__ float Bs[16][64];
  __shared__ float xd[24][68];
  __shared__ float Dtw[24][192];
  const int t = threadIdx.x;
  const int m0 = blockIdx.x * 64;
  const int s = m0 >> 11, l0 = m0 & 2047;
  for (int i = t; i < 24 * 192; i += 256) Dtw[i / 192][i % 192] = dtw_t[i];
  const int tx = t & 15, ty = t >> 4;
  const int lk = t >> 4, mq = t & 15;
  float acc[4][4];
#pragma unroll
  for (int i = 0; i < 4; ++i)
#pragma unroll
    for (int j = 0; j < 4; ++j) acc[i][j] = 0.0f;

  for (int k0 = 0; k0 < 192; k0 += 16) {
    const float4 a = *(const float4*)&xc[((size_t)s * 192 + k0 + lk) * 2048 + l0 + mq * 4];
    float4 b;
    if (mq < 14) b = *(const float4*)&xpw_t[(size_t)(k0 + lk) * 56 + mq * 4];
    else         b = make_float4(0.f, 0.f, 0.f, 0.f);
    __syncthreads();
    *(float4*)&As[lk][mq * 4] = a;
    *(float4*)&Bs[lk][mq * 4] = b;
    __syncthreads();
#pragma unroll
    for (int k = 0; k < 16; ++k) {
      const float4 av = *(const float4*)&As[k][tx * 4];
      const float4 bv = *(const float4*)&Bs[k][ty * 4];
      const float a4[4] = {av.x, av.y, av.z, av.w};
      const float b4[4] = {bv.x, bv.y, bv.z, bv.w};
#pragma unroll
      for (int i = 0; i < 4; ++i)
#pragma unroll
        for (int j = 0; j < 4; ++j) acc[i][j] = fmaf(a4[i], b4[j], acc[i][j]);
    }
  }
  const int nbase = ty * 4;
  if (nbase < 24) {
#pragma unroll
    for (int j = 0; j < 4; ++j)
#pragma unroll
      for (int i = 0; i < 4; ++i) xd[nbase + j][tx * 4 + i] = acc[i][j];
  } else if (nbase < 56) {
#pragma unroll
    for (int i = 0; i < 4; ++i) {
      float4 v; v.x = acc[i][0]; v.y = acc[i][1]; v.z = acc[i][2]; v.w = acc[i][3];
      *(float4*)&bc[(size_t)(m0 + tx * 4 + i) * 32 + (nbase - 24)] = v;
    }
  }
  __syncthreads();
#pragma unroll
  for (int dc = 0; dc < 3; ++dc) {
    float a2[4][4];
#pragma unroll
    for (int i = 0; i < 4; ++i)
#pragma unroll
      for (int j = 0; j < 4; ++j) a2[i][j] = 0.0f;
    const int d0 = dc * 64 + ty * 4;
#pragma unroll
    for (int r = 0; r < 24; ++r) {
      const float4 av = *(const float4*)&xd[r][tx * 4];
      const float4 bv = *(const float4*)&Dtw[r][d0];
      const float a4[4] = {av.x, av.y, av.z, av.w};
      const float b4[4] = {bv.x, bv.y, bv.z, bv.w};
#pragma unroll
      for (int i = 0; i < 4; ++i)
#pragma unroll
        for (int j = 0; j < 4; ++j) a2[i][j] = fmaf(a4[i], b4[j], a2[i][j]);
    }
#pragma unroll
    for (int j = 0; j < 4; ++j) {
      const int d = d0 + j;
      const float bb = dtb[d];
      float4 v;
      v.x = softplusf(a2[0][j] + bb);
      v.y = softplusf(a2[1][j] + bb);
      v.z = softplusf(a2[2][j] + bb);
      v.w = softplusf(a2[3][j] + bb);
      *(float4*)&delta[((size_t)s * 192 + d) * 2048 + l0 + tx * 4] = v;
    }
  }
}

// ---------------------------------------------------------------------------
// scanA: per-chunk gain G = exp(a*sum(delta)) and zero-init end state hend.
template<int DIR>
__launch_bounds__(256)
__global__ void k_scanA(const float* __restrict__ delta, const float* __restrict__ xc,
                        const float* __restrict__ bc, const float* __restrict__ A_log,
                        const float* __restrict__ Ab_log,
                        float* __restrict__ G, float* __restrict__ hc) {
  __shared__ float dch[16][132];
  __shared__ float uch[16][132];
  __shared__ float bsn[16][132];   // B transposed: [n][l]
  const int t = threadIdx.x;
  const int dl = t >> 4, n = t & 15;
  const int dg = blockIdx.x;
  const int s  = blockIdx.y;
  const int tc = blockIdx.z;
  const int d = dg * 16 + dl;
  const int base_l = DIR ? (LQ - CLEN * (tc + 1)) : (CLEN * tc);
  const float a = -__expf((DIR ? Ab_log : A_log)[d * 16 + n]);

  const size_t rb = ((size_t)s * 192 + dg * 16) * 2048 + base_l;
#pragma unroll
  for (int it = 0; it < 2; ++it) {
    const int i = t + it * 256;
    const int row = i >> 5, c4 = (i & 31) * 4;
    *(float4*)&dch[row][c4] = *(const float4*)&delta[rb + (size_t)row * 2048 + c4];
    *(float4*)&uch[row][c4] = *(const float4*)&xc[rb + (size_t)row * 2048 + c4];
  }
  const size_t bb = ((size_t)s * 2048 + base_l) * 32;
#pragma unroll
  for (int it = 0; it < 2; ++it) {
    const int i = t + it * 256;
    const int l = i >> 2, nq = (i & 3) * 4;
    F4 v; v.v = *(const float4*)&bc[bb + (size_t)l * 32 + nq];
#pragma unroll
    for (int k = 0; k < 4; ++k) bsn[nq + k][l] = v.a[k];
  }
  __syncthreads();
  float h = 0.0f, S = 0.0f;
#pragma unroll 4
  for (int qx = 0; qx < 32; ++qx) {
    const int q = DIR ? (31 - qx) : qx;
    const int lq = q * 4;
    F4 d4, u4, b4;
    d4.v = *(const float4*)&dch[dl][lq];
    u4.v = *(const float4*)&uch[dl][lq];
    b4.v = *(const float4*)&bsn[n][lq];
#pragma unroll
    for (int jj = 0; jj < 4; ++jj) {
      const int j = DIR ? (3 - jj) : jj;
      const float dlt = d4.a[j];
      const float dA = __expf(a * dlt);
      h = fmaf(dA, h, dlt * u4.a[j] * b4.a[j]);
      S += dlt;
    }
  }
  const size_t idx = (((size_t)(s * 2 + DIR) * NCHK + tc) * 192 + d) * 16 + n;
  G[idx] = __expf(a * S);
  hc[idx] = h;
}

// scanB: sequential carry scan over chunks; hc[tc] := h_in(tc) (in place).
__global__ void k_scanB(const float* __restrict__ G, float* __restrict__ hc) {
  const int gid = blockIdx.x * 256 + threadIdx.x;
  const int sd2 = gid / 3072;
  const int dn = gid % 3072;
  float h = 0.0f;
#pragma unroll
  for (int tc = 0; tc < NCHK; ++tc) {
    const size_t idx = ((size_t)sd2 * NCHK + tc) * 3072 + dn;
    const float g = G[idx];
    const float he = hc[idx];
    hc[idx] = h;
    h = fmaf(g, h, he);
  }
}

// scanC: re-run chunk seeded with h_in, emit y (DPP rotation reduce).
template<int DIR>
__launch_bounds__(256)
__global__ void k_scanC(const float* __restrict__ delta, const float* __restrict__ xc,
                        const float* __restrict__ bc, const float* __restrict__ A_log,
                        const float* __restrict__ Ab_log, const float* __restrict__ hc,
                        float* __restrict__ yf, float* __restrict__ yb) {
  __shared__ float dch[16][132];
  __shared__ float uch[16][132];
  __shared__ float bsn[16][132];
  __shared__ float csn[16][132];
  const int t = threadIdx.x;
  const int dl = t >> 4, n = t & 15;
  const int dg = blockIdx.x;
  const int s  = blockIdx.y;
  const int tc = blockIdx.z;
  const int d = dg * 16 + dl;
  const int base_l = DIR ? (LQ - CLEN * (tc + 1)) : (CLEN * tc);
  const float a = -__expf((DIR ? Ab_log : A_log)[d * 16 + n]);

  const size_t rb = ((size_t)s * 192 + dg * 16) * 2048 + base_l;
#pragma unroll
  for (int it = 0; it < 2; ++it) {
    const int i = t + it * 256;
    const int row = i >> 5, c4 = (i & 31) * 4;
    *(float4*)&dch[row][c4] = *(const float4*)&delta[rb + (size_t)row * 2048 + c4];
    *(float4*)&uch[row][c4] = *(const float4*)&xc[rb + (size_t)row * 2048 + c4];
  }
  const size_t bb = ((size_t)s * 2048 + base_l) * 32;
#pragma unroll
  for (int it = 0; it < 4; ++it) {
    const int i = t + it * 256;
    const int l = i >> 3, cq = (i & 7) * 4;
    F4 v; v.v = *(const float4*)&bc[bb + (size_t)l * 32 + cq];
    if (cq < 16) {
#pragma unroll
      for (int k = 0; k < 4; ++k) bsn[cq + k][l] = v.a[k];
    } else {
#pragma unroll
      for (int k = 0; k < 4; ++k) csn[cq - 16 + k][l] = v.a[k];
    }
  }
  const size_t idx = (((size_t)(s * 2 + DIR) * NCHK + tc) * 192 + d) * 16 + n;
  float h = hc[idx];
  __syncthreads();
  float* yrow = &(DIR ? yb : yf)[((size_t)s * 192 + d) * 2048 + base_l];
#pragma unroll 2
  for (int ww = 0; ww < 8; ++ww) {
    const int w = DIR ? (7 - ww) : ww;
    float ykeep = 0.0f;
#pragma unroll
    for (int qq = 0; qq < 4; ++qq) {
      const int q = DIR ? (3 - qq) : qq;
      const int lq = w * 16 + q * 4;
      F4 d4, u4, b4, c4;
      d4.v = *(const float4*)&dch[dl][lq];
      u4.v = *(const float4*)&uch[dl][lq];
      b4.v = *(const float4*)&bsn[n][lq];
      c4.v = *(const float4*)&csn[n][lq];
#pragma unroll
      for (int jj = 0; jj < 4; ++jj) {
        const int j = DIR ? (3 - jj) : jj;
        const float dlt = d4.a[j];
        const float dA = __expf(a * dlt);
        h = fmaf(dA, h, dlt * u4.a[j] * b4.a[j]);
        float yv = h * c4.a[j];
        yv = dpp_add<0x128>(yv);
        yv = dpp_add<0x124>(yv);
        yv = dpp_add<0x122>(yv);
        yv = dpp_add<0x121>(yv);
        ykeep = (q * 4 + j == n) ? yv : ykeep;
      }
    }
    yrow[w * 16 + n] = ykeep;
  }
}

// ---------------------------------------------------------------------------
// K4b: combine fwd+bwd+2Du || z, transpose to position-major bf16 A-buffer.
#define SWC(l) (((l >> 2) & 7) << 3)
__launch_bounds__(256)
__global__ void k_combine(const float* __restrict__ yf, const float* __restrict__ yb,
                          const float* __restrict__ xc, const float* __restrict__ Dvec,
                          u16* __restrict__ Abuf) {
  __shared__ u16 T[64][72];
  const int t = threadIdx.x;
  const int cg = blockIdx.x;                 // 0..5
  const int s  = blockIdx.y;                 // 0..11
  const int l0 = blockIdx.z * 64;            // 0..31 chunks
  const int c0 = (cg < 3 ? cg : cg - 3) * 64;
#pragma unroll
  for (int i = 0; i < 4; ++i) {
    const int idx = t + i * 256;             // 1024
    const int cr = idx >> 4, lq = (idx & 15) * 4;
    const size_t off = ((size_t)s * 192 + c0 + cr) * 2048 + l0 + lq;
    F4 v;
    if (cg < 3) {
      F4 f, g, u;
      f.v = *(const float4*)&yf[off];
      g.v = *(const float4*)&yb[off];
      u.v = *(const float4*)&xc[off];
      const float dv2 = 2.0f * Dvec[c0 + cr];
#pragma unroll
      for (int j = 0; j < 4; ++j) v.a[j] = f.a[j] + g.a[j] + dv2 * u.a[j];
    } else {
      v.v = *(const float4*)&xc[off];
    }
#pragma unroll
    for (int j = 0; j < 4; ++j) {
      const int l = lq + j;
      T[l][cr ^ SWC(l)] = f2bf(v.a[j]);
    }
  }
  __syncthreads();
  const int ccol = (cg < 3) ? cg * 64 : 192 + (cg - 3) * 64;
#pragma unroll
  for (int i = 0; i < 2; ++i) {
    const int idx = t + i * 256;             // 512
    const int l = idx >> 3, cq = (idx & 7) * 8;
    const u16x8 v = *(const u16x8*)&T[l][cq ^ SWC(l)];
    *(u16x8*)&Abuf[((size_t)s * 2048 + l0 + l) * 384 + ccol + cq] = v;
  }
}

// ---------------------------------------------------------------------------
// K5: out_proj GEMM via MFMA bf16. A = Abuf[m][384] bf16, B rows = w[c][k] bf16.
__launch_bounds__(256)
__global__ void k_outproj(const u16* __restrict__ Abuf, const u16* __restrict__ wbf,
                          const float* __restrict__ bias, float* __restrict__ out) {
  __shared__ __align__(16) char smem[34816];
  u16 (*As)[72] = (u16(*)[72])smem;                 // [128][72]
  u16 (*Bs)[72] = (u16(*)[72])(smem + 18432);       // [64][72]
  const int t = threadIdx.x;
  const int m0 = blockIdx.x * BM;
  const int n0 = blockIdx.y * BN;
  const int lane = t & 63, wid = t >> 6;
  const int wm = wid >> 1, wn = wid & 1;
  const int lr = lane & 15, lg = lane >> 4;
  f32x4 acc[4][2];
#pragma unroll
  for (int i = 0; i < 4; ++i)
#pragma unroll
    for (int j = 0; j < 2; ++j) acc[i][j] = (f32x4){0.f, 0.f, 0.f, 0.f};

  for (int k0 = 0; k0 < 384; k0 += BK) {
    u16x8 a_ld[4];
#pragma unroll
    for (int i = 0; i < 4; ++i) {
      const int idx = t + i * 256;                  // 1024
      const int row = idx >> 3, kq = (idx & 7) * 8;
      a_ld[i] = *(const u16x8*)&Abuf[(size_t)(m0 + row) * 384 + k0 + kq];
    }
    u16x8 b_ld[2];
#pragma unroll
    for (int i = 0; i < 2; ++i) {
      const int idx = t + i * 256;
      const int n = idx >> 3, kq = (idx & 7) * 8;
      b_ld[i] = *(const u16x8*)&wbf[(size_t)(n0 + n) * 384 + k0 + kq];
    }
    __syncthreads();
#pragma unroll
    for (int i = 0; i < 4; ++i) {
      const int idx = t + i * 256;
      const int row = idx >> 3, kq = (idx & 7) * 8;
      *(u16x8*)&As[row][kq] = a_ld[i];
    }
#pragma unroll
    for (int i = 0; i < 2; ++i) {
      const int idx = t + i * 256;
      const int n = idx >> 3, kq = (idx & 7) * 8;
      *(u16x8*)&Bs[n][kq] = b_ld[i];
    }
    __syncthreads();
#pragma unroll
    for (int kh = 0; kh < BK; kh += 32) {
      s16x8 af[4], bf[2];
#pragma unroll
      for (int mi = 0; mi < 4; ++mi)
        af[mi] = *(const s16x8*)&As[wm * 64 + mi * 16 + lr][kh + lg * 8];
#pragma unroll
      for (int ni = 0; ni < 2; ++ni)
        bf[ni] = *(const s16x8*)&Bs[wn * 32 + ni * 16 + lr][kh + lg * 8];
#pragma unroll
      for (int mi = 0; mi < 4; ++mi)
#pragma unroll
        for (int ni = 0; ni < 2; ++ni)
          acc[mi][ni] = __builtin_amdgcn_mfma_f32_16x16x32_bf16(af[mi], bf[ni], acc[mi][ni], 0, 0, 0);
    }
    __syncthreads();
  }
  // epilogue: row-major out via LDS
  float (*T)[68] = (float(*)[68])smem;              // [128][68]
#pragma unroll
  for (int mi = 0; mi < 4; ++mi)
#pragma unroll
    for (int ni = 0; ni < 2; ++ni) {
      const int c_loc = wn * 32 + ni * 16 + lr;
      const int m_loc = wm * 64 + mi * 16 + lg * 4;
#pragma unroll
      for (int r = 0; r < 4; ++r) T[m_loc + r][c_loc] = acc[mi][ni][r];
    }
  __syncthreads();
#pragma unroll
  for (int i = 0; i < 8; ++i) {
    const int idx = t + i * 256;                    // 2048
    const int m = idx >> 4, cq = (idx & 15) * 4;
    float4 v = *(const float4*)&T[m][cq];
    const float4 bb = *(const float4*)&bias[n0 + cq];
    v.x += bb.x; v.y += bb.y; v.z += bb.z; v.w += bb.w;
    *(float4*)&out[(size_t)(m0 + m) * 384 + n0 + cq] = v;
  }
}

// ---------------------------------------------------------------------------
extern "C" void kernel_launch(void* const* d_in, const int* in_sizes, int n_in,
                              void* d_out, int out_size, void* d_ws, size_t ws_size,
                              hipStream_t stream) {
  const float* x     = (const float*)d_in[0];
  const float* inw   = (const float*)d_in[1];
  const float* inb   = (const float*)d_in[2];
  const float* convw = (const float*)d_in[3];
  const float* convb = (const float*)d_in[4];
  const float* alog  = (const float*)d_in[5];
  const float* ablog = (const float*)d_in[6];
  const float* Dv    = (const float*)d_in[7];
  const float* xpw   = (const float*)d_in[8];
  const float* dtw   = (const float*)d_in[9];
  const float* dtb   = (const float*)d_in[10];
  const float* outw  = (const float*)d_in[11];
  const float* outb  = (const float*)d_in[12];
  float* out = (float*)d_out;

  float* ws = (float*)d_ws;
  float* xp_t  = ws;                       // 9437184
  float* xc    = xp_t + 9437184;           // 4718592
  float* delta = xc + 4718592;             // 4718592
  float* bc    = delta + 4718592;          // 786432
  float* xpw_t = bc + 786432;              // 10752
  float* dtw_t = xpw_t + 10752;            // 4608
  float* G     = dtw_t + 4608;             // 1179648
  float* hc    = G + 1179648;              // 1179648
  u16*   winb  = (u16*)(hc + 1179648);     // 147456 u16
  u16*   woutb = winb + 147456;            // 147456 u16
  // yf/yb alias xp_t (dead after conv); Abuf aliases delta (dead after scanC)
  float* yf = xp_t;
  float* yb = xp_t + 4718592;
  u16*   Abuf = (u16*)delta;

  hipLaunchKernelGGL(k_prep,      dim3(96),         dim3(256), 0, stream, xpw, dtw, inw, outw, xpw_t, dtw_t, winb, woutb);
  hipLaunchKernelGGL(k_inproj,    dim3(192, 6),     dim3(256), 0, stream, x, winb, inb, xp_t);
  hipLaunchKernelGGL(k_conv,      dim3(18432),      dim3(256), 0, stream, xp_t, convw, convb, xc);
  hipLaunchKernelGGL(k_xproj,     dim3(384),        dim3(256), 0, stream, xc, xpw_t, dtw_t, dtb, delta, bc);
  hipLaunchKernelGGL((k_scanA<0>),dim3(12, 12, 16), dim3(256), 0, stream, delta, xc, bc, alog, ablog, G, hc);
  hipLaunchKernelGGL((k_scanA<1>),dim3(12, 12, 16), dim3(256), 0, stream, delta, xc, bc, alog, ablog, G, hc);
  hipLaunchKernelGGL(k_scanB,     dim3(288),        dim3(256), 0, stream, G, hc);
  hipLaunchKernelGGL((k_scanC<0>),dim3(12, 12, 16), dim3(256), 0, stream, delta, xc, bc, alog, ablog, hc, yf, yb);
  hipLaunchKernelGGL((k_scanC<1>),dim3(12, 12, 16), dim3(256), 0, stream, delta, xc, bc, alog, ablog, hc, yf, yb);
  hipLaunchKernelGGL(k_combine,   dim3(6, 12, 32),  dim3(256), 0, stream, yf, yb, xc, Dv, Abuf);
  hipLaunchKernelGGL(k_outproj,   dim3(192, 6),     dim3(256), 0, stream, Abuf, woutb, outb, out);
}

// Round 6
// 347.546 us; speedup vs baseline: 3.3822x; 1.0871x over previous
//
#include <hip/hip_runtime.h>
#include <hip/hip_bf16.h>
#include <math.h>

// Problem constants
#define NSQ   12      // b*F sequences
#define LQ    2048    // per-sequence length
#define DIMQ  384
#define DIQ   192     // d_in
#define RKQ   24      // dt rank
#define NCHK  16      // scan chunks
#define CLEN  128     // chunk length (LQ/NCHK)

// GEMM tiling
#define BM 128
#define BN 64
#define BK 64

typedef unsigned short u16;
typedef __attribute__((ext_vector_type(8))) short s16x8;
typedef __attribute__((ext_vector_type(4))) float f32x4;
typedef __attribute__((ext_vector_type(4))) unsigned short u16x4;
typedef __attribute__((ext_vector_type(8))) unsigned short u16x8;

__device__ __forceinline__ float siluf(float x) {
  return x / (1.0f + __expf(-x));
}
__device__ __forceinline__ float softplusf(float x) {
  return (x > 20.0f) ? x : log1pf(expf(x));
}
__device__ __forceinline__ u16 f2bf(float f) {   // RNE f32->bf16
  unsigned int u = __float_as_uint(f);
  u += 0x7FFFu + ((u >> 16) & 1u);
  return (u16)(u >> 16);
}
__device__ __forceinline__ float bf2f(u16 h) {
  return __uint_as_float(((unsigned int)h) << 16);
}

union F4 { float4 v; float a[4]; };

// VALU-only 16-lane rotation-add (DPP row_ror). All lanes end with the sum.
template<int CTRL>
__device__ __forceinline__ float dpp_add(float x) {
  union { float f; int i; } u, r;
  u.f = x;
  r.i = __builtin_amdgcn_update_dpp(0, u.i, CTRL, 0xF, 0xF, true);
  return x + r.f;
}

// ---------------------------------------------------------------------------
// K0: weight prep. winb/woutb = bf16 GEMM weights. Wcomb (224x192) =
// [dtw @ xpw[:24] ; xpw[24:56]] split into hi/lo bf16 for split-bf16 MFMA.
__global__ void k_prep(const float* __restrict__ xpw, const float* __restrict__ dtw,
                       const float* __restrict__ inw, const float* __restrict__ outw,
                       u16* __restrict__ winb, u16* __restrict__ woutb,
                       u16* __restrict__ wc_hi, u16* __restrict__ wc_lo) {
  int t = threadIdx.x + blockIdx.x * blockDim.x;
  int stride = blockDim.x * gridDim.x;
  for (int i = t; i < DIMQ * DIMQ; i += stride) {
    winb[i]  = f2bf(inw[i]);
    woutb[i] = f2bf(outw[i]);
  }
  for (int i = t; i < 224 * 192; i += stride) {
    const int r = i / 192, k = i % 192;
    float v;
    if (r < 192) {            // W_eff[r][k] = sum_q dtw[r][q]*xpw[q][k]
      float s = 0.0f;
      for (int q = 0; q < RKQ; ++q) s = fmaf(dtw[r * RKQ + q], xpw[q * 192 + k], s);
      v = s;
    } else {
      v = xpw[(24 + (r - 192)) * 192 + k];
    }
    const u16 hi = f2bf(v);
    wc_hi[i] = hi;
    wc_lo[i] = f2bf(v - bf2f(hi));
  }
}

// ---------------------------------------------------------------------------
// K1: in_proj GEMM via MFMA bf16. Output channel-major xp_t.
__launch_bounds__(256)
__global__ void k_inproj(const float* __restrict__ x, const u16* __restrict__ wbf,
                         const float* __restrict__ bias, float* __restrict__ xp_t) {
  __shared__ __align__(16) char smem[33792];
  u16 (*As)[72] = (u16(*)[72])smem;                 // [128][72]
  u16 (*Bs)[72] = (u16(*)[72])(smem + 18432);       // [64][72]
  const int t = threadIdx.x;
  const int m0 = blockIdx.x * BM;
  const int n0 = blockIdx.y * BN;
  const int lane = t & 63, wid = t >> 6;
  const int wm = wid >> 1, wn = wid & 1;
  const int lr = lane & 15, lg = lane >> 4;
  f32x4 acc[4][2];
#pragma unroll
  for (int i = 0; i < 4; ++i)
#pragma unroll
    for (int j = 0; j < 2; ++j) acc[i][j] = (f32x4){0.f, 0.f, 0.f, 0.f};

  for (int k0 = 0; k0 < 384; k0 += BK) {
    float4 a_ld[8];
#pragma unroll
    for (int i = 0; i < 8; ++i) {
      const int idx = t + i * 256;
      const int row = idx >> 4, kq = (idx & 15) * 4;
      a_ld[i] = *(const float4*)&x[(size_t)(m0 + row) * 384 + k0 + kq];
    }
    u16x8 b_ld[2];
#pragma unroll
    for (int i = 0; i < 2; ++i) {
      const int idx = t + i * 256;
      const int n = idx >> 3, kq = (idx & 7) * 8;
      b_ld[i] = *(const u16x8*)&wbf[(size_t)(n0 + n) * 384 + k0 + kq];
    }
    __syncthreads();
#pragma unroll
    for (int i = 0; i < 8; ++i) {
      const int idx = t + i * 256;
      const int row = idx >> 4, kq = (idx & 15) * 4;
      u16x4 p;
      p.x = f2bf(a_ld[i].x); p.y = f2bf(a_ld[i].y);
      p.z = f2bf(a_ld[i].z); p.w = f2bf(a_ld[i].w);
      *(u16x4*)&As[row][kq] = p;
    }
#pragma unroll
    for (int i = 0; i < 2; ++i) {
      const int idx = t + i * 256;
      const int n = idx >> 3, kq = (idx & 7) * 8;
      *(u16x8*)&Bs[n][kq] = b_ld[i];
    }
    __syncthreads();
#pragma unroll
    for (int kh = 0; kh < BK; kh += 32) {
      s16x8 af[4], bf[2];
#pragma unroll
      for (int mi = 0; mi < 4; ++mi)
        af[mi] = *(const s16x8*)&As[wm * 64 + mi * 16 + lr][kh + lg * 8];
#pragma unroll
      for (int ni = 0; ni < 2; ++ni)
        bf[ni] = *(const s16x8*)&Bs[wn * 32 + ni * 16 + lr][kh + lg * 8];
#pragma unroll
      for (int mi = 0; mi < 4; ++mi)
#pragma unroll
        for (int ni = 0; ni < 2; ++ni)
          acc[mi][ni] = __builtin_amdgcn_mfma_f32_16x16x32_bf16(af[mi], bf[ni], acc[mi][ni], 0, 0, 0);
    }
    __syncthreads();
  }
  float (*T)[132] = (float(*)[132])smem;            // [64][132]
#pragma unroll
  for (int mi = 0; mi < 4; ++mi)
#pragma unroll
    for (int ni = 0; ni < 2; ++ni) {
      const int c_loc = wn * 32 + ni * 16 + lr;
      const int m_loc = wm * 64 + mi * 16 + lg * 4;
      *(f32x4*)&T[c_loc][m_loc] = acc[mi][ni];
    }
  __syncthreads();
  const int s = m0 >> 11, p0 = m0 & 2047;
#pragma unroll
  for (int i = 0; i < 8; ++i) {
    const int idx = t + i * 256;
    const int c = idx >> 5, pq = (idx & 31) * 4;
    float4 v = *(const float4*)&T[c][pq];
    const float bv = bias[n0 + c];
    v.x += bv; v.y += bv; v.z += bv; v.w += bv;
    *(float4*)&xp_t[((size_t)s * 384 + n0 + c) * 2048 + p0 + pq] = v;
  }
}

// ---------------------------------------------------------------------------
// K2: grouped conv (k=3, SAME) + SiLU.
__global__ void k_conv(const float* __restrict__ xp_t, const float* __restrict__ cw,
                       const float* __restrict__ cb, float* __restrict__ xc) {
  const int idx = blockIdx.x * 256 + threadIdx.x;
  const int p = idx & 2047;
  const int sd = idx >> 11;
  const int d = sd % DIQ, s = sd / DIQ;
  const float* r0 = &xp_t[((size_t)s * 384 + 2 * d) * 2048];
  const float* r1 = r0 + 2048;
  const float w00 = cw[d * 6 + 0], w01 = cw[d * 6 + 1], w02 = cw[d * 6 + 2];
  const float w10 = cw[d * 6 + 3], w11 = cw[d * 6 + 4], w12 = cw[d * 6 + 5];
  float acc = cb[d];
  if (p > 0)    acc += w00 * r0[p - 1] + w10 * r1[p - 1];
  acc += w01 * r0[p] + w11 * r1[p];
  if (p < 2047) acc += w02 * r0[p + 1] + w12 * r1[p + 1];
  xc[idx] = siluf(acc);
}

// ---------------------------------------------------------------------------
// K3: fused x_proj + dt_proj as ONE split-bf16 MFMA GEMM.
// Wcomb (224 rows) @ u (192 x L). Rows 0..191 -> softplus(.+dtb) -> delta
// (channel-major); rows 192..223 -> bc[l][32]. Block = 64 l of one s; 4 waves
// each own a 16-l slice; 14 m-tiles of 16; K = 192 in 6 chunks of 32.
__launch_bounds__(256)
__global__ void k_xproj(const float* __restrict__ xc, const u16* __restrict__ wc_hi,
                        const u16* __restrict__ wc_lo, const float* __restrict__ dtb,
                        float* __restrict__ delta, float* __restrict__ bc) {
  __shared__ u16 Ah[224][40];
  __shared__ u16 Al[224][40];
  __shared__ u16 Bh[64][40];
  __shared__ u16 Bl[64][40];
  const int t = threadIdx.x;
  const int lane = t & 63, w = t >> 6;
  const int ln = lane & 15, lg = lane >> 4;
  const int blk = blockIdx.x;                 // 0..383
  const int s = blk >> 5, l0 = (blk & 31) * 64;
  f32x4 acc[14];
#pragma unroll
  for (int mi = 0; mi < 14; ++mi) acc[mi] = (f32x4){0.f, 0.f, 0.f, 0.f};

  for (int kc = 0; kc < 192; kc += 32) {
    // global loads -> regs
    u16x8 wah[4], wal[4];
#pragma unroll
    for (int i = 0; i < 4; ++i) {
      const int idx = t + i * 256;
      if (idx < 896) {
        const int r = idx >> 2, kg = (idx & 3) * 8;
        wah[i] = *(const u16x8*)&wc_hi[(size_t)r * 192 + kc + kg];
        wal[i] = *(const u16x8*)&wc_lo[(size_t)r * 192 + kc + kg];
      }
    }
    float4 uld[2];
#pragma unroll
    for (int i = 0; i < 2; ++i) {
      const int idx = t + i * 256;              // 0..511
      const int k = idx >> 4, lq = (idx & 15) * 4;
      uld[i] = *(const float4*)&xc[((size_t)s * 192 + kc + k) * 2048 + l0 + lq];
    }
    __syncthreads();
#pragma unroll
    for (int i = 0; i < 4; ++i) {
      const int idx = t + i * 256;
      if (idx < 896) {
        const int r = idx >> 2, kg = (idx & 3) * 8;
        *(u16x8*)&Ah[r][kg] = wah[i];
        *(u16x8*)&Al[r][kg] = wal[i];
      }
    }
#pragma unroll
    for (int i = 0; i < 2; ++i) {
      const int idx = t + i * 256;
      const int k = idx >> 4, lq = (idx & 15) * 4;
      F4 v; v.v = uld[i];
#pragma unroll
      for (int j = 0; j < 4; ++j) {
        const float f = v.a[j];
        const u16 hi = f2bf(f);
        Bh[lq + j][k] = hi;
        Bl[lq + j][k] = f2bf(f - bf2f(hi));
      }
    }
    __syncthreads();
    const s16x8 bh = *(const s16x8*)&Bh[w * 16 + ln][lg * 8];
    const s16x8 bl = *(const s16x8*)&Bl[w * 16 + ln][lg * 8];
#pragma unroll
    for (int mi = 0; mi < 14; ++mi) {
      const s16x8 ah = *(const s16x8*)&Ah[mi * 16 + ln][lg * 8];
      const s16x8 al = *(const s16x8*)&Al[mi * 16 + ln][lg * 8];
      acc[mi] = __builtin_amdgcn_mfma_f32_16x16x32_bf16(ah, bh, acc[mi], 0, 0, 0);
      acc[mi] = __builtin_amdgcn_mfma_f32_16x16x32_bf16(al, bh, acc[mi], 0, 0, 0);
      acc[mi] = __builtin_amdgcn_mfma_f32_16x16x32_bf16(ah, bl, acc[mi], 0, 0, 0);
    }
    __syncthreads();
  }
  // epilogue
  const int l = l0 + w * 16 + ln;
#pragma unroll
  for (int mi = 0; mi < 12; ++mi) {
    const int r0 = mi * 16 + lg * 4;
#pragma unroll
    for (int j = 0; j < 4; ++j) {
      const int r = r0 + j;
      delta[((size_t)s * 192 + r) * 2048 + l] = softplusf(acc[mi][j] + dtb[r]);
    }
  }
#pragma unroll
  for (int mi = 12; mi < 14; ++mi) {
    const int rr = (mi - 12) * 16 + lg * 4;
    float4 v;
    v.x = acc[mi][0]; v.y = acc[mi][1]; v.z = acc[mi][2]; v.w = acc[mi][3];
    *(float4*)&bc[((size_t)s * 2048 + l) * 32 + rr] = v;
  }
}

// ---------------------------------------------------------------------------
// scanA: per-chunk gain G = exp(a*sum(delta)) and zero-init end state hend.
template<int DIR>
__launch_bounds__(256)
__global__ void k_scanA(const float* __restrict__ delta, const float* __restrict__ xc,
                        const float* __restrict__ bc, const float* __restrict__ A_log,
                        const float* __restrict__ Ab_log,
                        float* __restrict__ G, float* __restrict__ hc) {
  __shared__ float dch[16][132];
  __shared__ float uch[16][132];
  __shared__ float bsn[16][132];   // B transposed: [n][l]
  const int t = threadIdx.x;
  const int dl = t >> 4, n = t & 15;
  const int dg = blockIdx.x;
  const int s  = blockIdx.y;
  const int tc = blockIdx.z;
  const int d = dg * 16 + dl;
  const int base_l = DIR ? (LQ - CLEN * (tc + 1)) : (CLEN * tc);
  const float a = -__expf((DIR ? Ab_log : A_log)[d * 16 + n]);

  const size_t rb = ((size_t)s * 192 + dg * 16) * 2048 + base_l;
#pragma unroll
  for (int it = 0; it < 2; ++it) {
    const int i = t + it * 256;
    const int row = i >> 5, c4 = (i & 31) * 4;
    *(float4*)&dch[row][c4] = *(const float4*)&delta[rb + (size_t)row * 2048 + c4];
    *(float4*)&uch[row][c4] = *(const float4*)&xc[rb + (size_t)row * 2048 + c4];
  }
  const size_t bb = ((size_t)s * 2048 + base_l) * 32;
#pragma unroll
  for (int it = 0; it < 2; ++it) {
    const int i = t + it * 256;
    const int l = i >> 2, nq = (i & 3) * 4;
    F4 v; v.v = *(const float4*)&bc[bb + (size_t)l * 32 + nq];
#pragma unroll
    for (int k = 0; k < 4; ++k) bsn[nq + k][l] = v.a[k];
  }
  __syncthreads();
  float h = 0.0f, S = 0.0f;
#pragma unroll 4
  for (int qx = 0; qx < 32; ++qx) {
    const int q = DIR ? (31 - qx) : qx;
    const int lq = q * 4;
    F4 d4, u4, b4;
    d4.v = *(const float4*)&dch[dl][lq];
    u4.v = *(const float4*)&uch[dl][lq];
    b4.v = *(const float4*)&bsn[n][lq];
#pragma unroll
    for (int jj = 0; jj < 4; ++jj) {
      const int j = DIR ? (3 - jj) : jj;
      const float dlt = d4.a[j];
      const float dA = __expf(a * dlt);
      h = fmaf(dA, h, dlt * u4.a[j] * b4.a[j]);
      S += dlt;
    }
  }
  const size_t idx = (((size_t)(s * 2 + DIR) * NCHK + tc) * 192 + d) * 16 + n;
  G[idx] = __expf(a * S);
  hc[idx] = h;
}

// scanB: sequential carry scan over chunks; hc[tc] := h_in(tc) (in place).
__global__ void k_scanB(const float* __restrict__ G, float* __restrict__ hc) {
  const int gid = blockIdx.x * 256 + threadIdx.x;
  const int sd2 = gid / 3072;
  const int dn = gid % 3072;
  float h = 0.0f;
#pragma unroll
  for (int tc = 0; tc < NCHK; ++tc) {
    const size_t idx = ((size_t)sd2 * NCHK + tc) * 3072 + dn;
    const float g = G[idx];
    const float he = hc[idx];
    hc[idx] = h;
    h = fmaf(g, h, he);
  }
}

// scanC: re-run chunk seeded with h_in, emit y (DPP rotation reduce).
template<int DIR>
__launch_bounds__(256)
__global__ void k_scanC(const float* __restrict__ delta, const float* __restrict__ xc,
                        const float* __restrict__ bc, const float* __restrict__ A_log,
                        const float* __restrict__ Ab_log, const float* __restrict__ hc,
                        float* __restrict__ yf, float* __restrict__ yb) {
  __shared__ float dch[16][132];
  __shared__ float uch[16][132];
  __shared__ float bsn[16][132];
  __shared__ float csn[16][132];
  const int t = threadIdx.x;
  const int dl = t >> 4, n = t & 15;
  const int dg = blockIdx.x;
  const int s  = blockIdx.y;
  const int tc = blockIdx.z;
  const int d = dg * 16 + dl;
  const int base_l = DIR ? (LQ - CLEN * (tc + 1)) : (CLEN * tc);
  const float a = -__expf((DIR ? Ab_log : A_log)[d * 16 + n]);

  const size_t rb = ((size_t)s * 192 + dg * 16) * 2048 + base_l;
#pragma unroll
  for (int it = 0; it < 2; ++it) {
    const int i = t + it * 256;
    const int row = i >> 5, c4 = (i & 31) * 4;
    *(float4*)&dch[row][c4] = *(const float4*)&delta[rb + (size_t)row * 2048 + c4];
    *(float4*)&uch[row][c4] = *(const float4*)&xc[rb + (size_t)row * 2048 + c4];
  }
  const size_t bb = ((size_t)s * 2048 + base_l) * 32;
#pragma unroll
  for (int it = 0; it < 4; ++it) {
    const int i = t + it * 256;
    const int l = i >> 3, cq = (i & 7) * 4;
    F4 v; v.v = *(const float4*)&bc[bb + (size_t)l * 32 + cq];
    if (cq < 16) {
#pragma unroll
      for (int k = 0; k < 4; ++k) bsn[cq + k][l] = v.a[k];
    } else {
#pragma unroll
      for (int k = 0; k < 4; ++k) csn[cq - 16 + k][l] = v.a[k];
    }
  }
  const size_t idx = (((size_t)(s * 2 + DIR) * NCHK + tc) * 192 + d) * 16 + n;
  float h = hc[idx];
  __syncthreads();
  float* yrow = &(DIR ? yb : yf)[((size_t)s * 192 + d) * 2048 + base_l];
#pragma unroll 2
  for (int ww = 0; ww < 8; ++ww) {
    const int w = DIR ? (7 - ww) : ww;
    float ykeep = 0.0f;
#pragma unroll
    for (int qq = 0; qq < 4; ++qq) {
      const int q = DIR ? (3 - qq) : qq;
      const int lq = w * 16 + q * 4;
      F4 d4, u4, b4, c4;
      d4.v = *(const float4*)&dch[dl][lq];
      u4.v = *(const float4*)&uch[dl][lq];
      b4.v = *(const float4*)&bsn[n][lq];
      c4.v = *(const float4*)&csn[n][lq];
#pragma unroll
      for (int jj = 0; jj < 4; ++jj) {
        const int j = DIR ? (3 - jj) : jj;
        const float dlt = d4.a[j];
        const float dA = __expf(a * dlt);
        h = fmaf(dA, h, dlt * u4.a[j] * b4.a[j]);
        float yv = h * c4.a[j];
        yv = dpp_add<0x128>(yv);
        yv = dpp_add<0x124>(yv);
        yv = dpp_add<0x122>(yv);
        yv = dpp_add<0x121>(yv);
        ykeep = (q * 4 + j == n) ? yv : ykeep;
      }
    }
    yrow[w * 16 + n] = ykeep;
  }
}

// ---------------------------------------------------------------------------
// K4b: combine fwd+bwd+2Du || z, transpose to position-major bf16 A-buffer.
#define SWC(l) (((l >> 2) & 7) << 3)
__launch_bounds__(256)
__global__ void k_combine(const float* __restrict__ yf, const float* __restrict__ yb,
                          const float* __restrict__ xc, const float* __restrict__ Dvec,
                          u16* __restrict__ Abuf) {
  __shared__ u16 T[64][72];
  const int t = threadIdx.x;
  const int cg = blockIdx.x;                 // 0..5
  const int s  = blockIdx.y;                 // 0..11
  const int l0 = blockIdx.z * 64;            // 0..31 chunks
  const int c0 = (cg < 3 ? cg : cg - 3) * 64;
#pragma unroll
  for (int i = 0; i < 4; ++i) {
    const int idx = t + i * 256;             // 1024
    const int cr = idx >> 4, lq = (idx & 15) * 4;
    const size_t off = ((size_t)s * 192 + c0 + cr) * 2048 + l0 + lq;
    F4 v;
    if (cg < 3) {
      F4 f, g, u;
      f.v = *(const float4*)&yf[off];
      g.v = *(const float4*)&yb[off];
      u.v = *(const float4*)&xc[off];
      const float dv2 = 2.0f * Dvec[c0 + cr];
#pragma unroll
      for (int j = 0; j < 4; ++j) v.a[j] = f.a[j] + g.a[j] + dv2 * u.a[j];
    } else {
      v.v = *(const float4*)&xc[off];
    }
#pragma unroll
    for (int j = 0; j < 4; ++j) {
      const int l = lq + j;
      T[l][cr ^ SWC(l)] = f2bf(v.a[j]);
    }
  }
  __syncthreads();
  const int ccol = (cg < 3) ? cg * 64 : 192 + (cg - 3) * 64;
#pragma unroll
  for (int i = 0; i < 2; ++i) {
    const int idx = t + i * 256;             // 512
    const int l = idx >> 3, cq = (idx & 7) * 8;
    const u16x8 v = *(const u16x8*)&T[l][cq ^ SWC(l)];
    *(u16x8*)&Abuf[((size_t)s * 2048 + l0 + l) * 384 + ccol + cq] = v;
  }
}

// ---------------------------------------------------------------------------
// K5: out_proj GEMM via MFMA bf16.
__launch_bounds__(256)
__global__ void k_outproj(const u16* __restrict__ Abuf, const u16* __restrict__ wbf,
                          const float* __restrict__ bias, float* __restrict__ out) {
  __shared__ __align__(16) char smem[34816];
  u16 (*As)[72] = (u16(*)[72])smem;                 // [128][72]
  u16 (*Bs)[72] = (u16(*)[72])(smem + 18432);       // [64][72]
  const int t = threadIdx.x;
  const int m0 = blockIdx.x * BM;
  const int n0 = blockIdx.y * BN;
  const int lane = t & 63, wid = t >> 6;
  const int wm = wid >> 1, wn = wid & 1;
  const int lr = lane & 15, lg = lane >> 4;
  f32x4 acc[4][2];
#pragma unroll
  for (int i = 0; i < 4; ++i)
#pragma unroll
    for (int j = 0; j < 2; ++j) acc[i][j] = (f32x4){0.f, 0.f, 0.f, 0.f};

  for (int k0 = 0; k0 < 384; k0 += BK) {
    u16x8 a_ld[4];
#pragma unroll
    for (int i = 0; i < 4; ++i) {
      const int idx = t + i * 256;
      const int row = idx >> 3, kq = (idx & 7) * 8;
      a_ld[i] = *(const u16x8*)&Abuf[(size_t)(m0 + row) * 384 + k0 + kq];
    }
    u16x8 b_ld[2];
#pragma unroll
    for (int i = 0; i < 2; ++i) {
      const int idx = t + i * 256;
      const int n = idx >> 3, kq = (idx & 7) * 8;
      b_ld[i] = *(const u16x8*)&wbf[(size_t)(n0 + n) * 384 + k0 + kq];
    }
    __syncthreads();
#pragma unroll
    for (int i = 0; i < 4; ++i) {
      const int idx = t + i * 256;
      const int row = idx >> 3, kq = (idx & 7) * 8;
      *(u16x8*)&As[row][kq] = a_ld[i];
    }
#pragma unroll
    for (int i = 0; i < 2; ++i) {
      const int idx = t + i * 256;
      const int n = idx >> 3, kq = (idx & 7) * 8;
      *(u16x8*)&Bs[n][kq] = b_ld[i];
    }
    __syncthreads();
#pragma unroll
    for (int kh = 0; kh < BK; kh += 32) {
      s16x8 af[4], bf[2];
#pragma unroll
      for (int mi = 0; mi < 4; ++mi)
        af[mi] = *(const s16x8*)&As[wm * 64 + mi * 16 + lr][kh + lg * 8];
#pragma unroll
      for (int ni = 0; ni < 2; ++ni)
        bf[ni] = *(const s16x8*)&Bs[wn * 32 + ni * 16 + lr][kh + lg * 8];
#pragma unroll
      for (int mi = 0; mi < 4; ++mi)
#pragma unroll
        for (int ni = 0; ni < 2; ++ni)
          acc[mi][ni] = __builtin_amdgcn_mfma_f32_16x16x32_bf16(af[mi], bf[ni], acc[mi][ni], 0, 0, 0);
    }
    __syncthreads();
  }
  float (*T)[68] = (float(*)[68])smem;              // [128][68]
#pragma unroll
  for (int mi = 0; mi < 4; ++mi)
#pragma unroll
    for (int ni = 0; ni < 2; ++ni) {
      const int c_loc = wn * 32 + ni * 16 + lr;
      const int m_loc = wm * 64 + mi * 16 + lg * 4;
#pragma unroll
      for (int r = 0; r < 4; ++r) T[m_loc + r][c_loc] = acc[mi][ni][r];
    }
  __syncthreads();
#pragma unroll
  for (int i = 0; i < 8; ++i) {
    const int idx = t + i * 256;
    const int m = idx >> 4, cq = (idx & 15) * 4;
    float4 v = *(const float4*)&T[m][cq];
    const float4 bb = *(const float4*)&bias[n0 + cq];
    v.x += bb.x; v.y += bb.y; v.z += bb.z; v.w += bb.w;
    *(float4*)&out[(size_t)(m0 + m) * 384 + n0 + cq] = v;
  }
}

// ---------------------------------------------------------------------------
extern "C" void kernel_launch(void* const* d_in, const int* in_sizes, int n_in,
                              void* d_out, int out_size, void* d_ws, size_t ws_size,
                              hipStream_t stream) {
  const float* x     = (const float*)d_in[0];
  const float* inw   = (const float*)d_in[1];
  const float* inb   = (const float*)d_in[2];
  const float* convw = (const float*)d_in[3];
  const float* convb = (const float*)d_in[4];
  const float* alog  = (const float*)d_in[5];
  const float* ablog = (const float*)d_in[6];
  const float* Dv    = (const float*)d_in[7];
  const float* xpw   = (const float*)d_in[8];
  const float* dtw   = (const float*)d_in[9];
  const float* dtb   = (const float*)d_in[10];
  const float* outw  = (const float*)d_in[11];
  const float* outb  = (const float*)d_in[12];
  float* out = (float*)d_out;

  float* ws = (float*)d_ws;
  float* xp_t  = ws;                       // 9437184
  float* xc    = xp_t + 9437184;           // 4718592
  float* delta = xc + 4718592;             // 4718592
  float* bc    = delta + 4718592;          // 786432
  float* G     = bc + 786432;              // 1179648
  float* hc    = G + 1179648;              // 1179648
  u16*   winb  = (u16*)(hc + 1179648);     // 147456 u16
  u16*   woutb = winb + 147456;            // 147456 u16
  u16*   wc_hi = woutb + 147456;           // 43008 u16
  u16*   wc_lo = wc_hi + 43008;            // 43008 u16
  // yf/yb alias xp_t (dead after conv); Abuf aliases delta (dead after scanC)
  float* yf = xp_t;
  float* yb = xp_t + 4718592;
  u16*   Abuf = (u16*)delta;

  hipLaunchKernelGGL(k_prep,      dim3(96),         dim3(256), 0, stream, xpw, dtw, inw, outw, winb, woutb, wc_hi, wc_lo);
  hipLaunchKernelGGL(k_inproj,    dim3(192, 6),     dim3(256), 0, stream, x, winb, inb, xp_t);
  hipLaunchKernelGGL(k_conv,      dim3(18432),      dim3(256), 0, stream, xp_t, convw, convb, xc);
  hipLaunchKernelGGL(k_xproj,     dim3(384),        dim3(256), 0, stream, xc, wc_hi, wc_lo, dtb, delta, bc);
  hipLaunchKernelGGL((k_scanA<0>),dim3(12, 12, 16), dim3(256), 0, stream, delta, xc, bc, alog, ablog, G, hc);
  hipLaunchKernelGGL((k_scanA<1>),dim3(12, 12, 16), dim3(256), 0, stream, delta, xc, bc, alog, ablog, G, hc);
  hipLaunchKernelGGL(k_scanB,     dim3(288),        dim3(256), 0, stream, G, hc);
  hipLaunchKernelGGL((k_scanC<0>),dim3(12, 12, 16), dim3(256), 0, stream, delta, xc, bc, alog, ablog, hc, yf, yb);
  hipLaunchKernelGGL((k_scanC<1>),dim3(12, 12, 16), dim3(256), 0, stream, delta, xc, bc, alog, ablog, hc, yf, yb);
  hipLaunchKernelGGL(k_combine,   dim3(6, 12, 32),  dim3(256), 0, stream, yf, yb, xc, Dv, Abuf);
  hipLaunchKernelGGL(k_outproj,   dim3(192, 6),     dim3(256), 0, stream, Abuf, woutb, outb, out);
}